// Round 1
// baseline (1113.649 us; speedup 1.0000x reference)
//
#include <hip/hip_runtime.h>
#include <stdint.h>

// Problem constants (fixed by reference setup_inputs)
#define D      64
#define K      1024
#define HW     1024          // H*W = 32*32
#define NROWS  65536         // B*H*W = 64*1024
#define NELEM  (NROWS * D)   // 4,194,304
#define CHUNK  128           // codes staged in LDS per chunk
#define SPLITS 4
#define CODES_PER_SPLIT (K / SPLITS)   // 256

// Output layout (floats, concatenated in reference return order)
#define O_ZQ   0
#define O_LOSS 4194304
#define O_IDX  4194305
#define O_NCS  4259841
#define O_EMAW 4260865
#define O_EMB  4326401

// Workspace layout
#define WS_COUNTS 0          // 1024 f32
#define WS_DW     1024       // 65536 f32
#define WS_LOSS   66560      // 1 f32
#define WS_N      66561      // 1 f32
#define WS_ZERO_BYTES 266248 // (66562 f32) bytes, 8-aligned
#define WS_KEYS_BYTES 266248 // u64 keys start here (65536 * 8 bytes)

// ---------------------------------------------------------------------------
// Kernel 1: split-K distance scan + per-row argmin via packed u64 atomicMin.
// grid = (256 row-blocks, 4 K-splits), block = 256 threads (1 thread = 1 row)
// ---------------------------------------------------------------------------
__global__ __launch_bounds__(256, 4) void vq_dist_kernel(
    const float* __restrict__ z, const float* __restrict__ emb,
    unsigned long long* __restrict__ keys)
{
    __shared__ float4 se[CHUNK * 16];   // 128 codes x 64 f32 = 32 KB
    __shared__ float  sesq[CHUNK];

    const int tid   = threadIdx.x;
    const int n     = blockIdx.x * 256 + tid;     // row id
    const int split = blockIdx.y;                 // 0..3
    const int b     = n >> 10;
    const int hw    = n & 1023;

    // Load this row of z into registers: z[b][d][hw], d-stride = HW floats.
    // Lanes have consecutive hw -> every load is wave-coalesced (256B).
    const float* zb = z + (size_t)b * D * HW + hw;
    float4 zr[16];
#pragma unroll
    for (int i = 0; i < 16; ++i) {
        zr[i].x = zb[(i * 4 + 0) * HW];
        zr[i].y = zb[(i * 4 + 1) * HW];
        zr[i].z = zb[(i * 4 + 2) * HW];
        zr[i].w = zb[(i * 4 + 3) * HW];
    }

    float best = INFINITY;
    int   bk   = 0;
    const float4* emb4 = (const float4*)emb;

    for (int ch = 0; ch < CODES_PER_SPLIT / CHUNK; ++ch) {
        const int cbase = split * CODES_PER_SPLIT + ch * CHUNK;
        __syncthreads();   // protect previous chunk's readers
#pragma unroll
        for (int i = 0; i < (CHUNK * 16) / 256; ++i)   // 8 float4 per thread
            se[i * 256 + tid] = emb4[(size_t)cbase * 16 + i * 256 + tid];
        __syncthreads();
        if (tid < CHUNK) {   // per-chunk ||e_k||^2
            float a = 0.f;
#pragma unroll
            for (int i = 0; i < 16; ++i) {
                float4 e = se[tid * 16 + i];
                a += e.x * e.x + e.y * e.y + e.z * e.z + e.w * e.w;
            }
            sesq[tid] = a;
        }
        __syncthreads();

        for (int c = 0; c < CHUNK; ++c) {
            float a0 = 0.f, a1 = 0.f, a2 = 0.f, a3 = 0.f;
#pragma unroll
            for (int i = 0; i < 16; ++i) {   // uniform ds_read_b128 broadcast
                float4 e = se[c * 16 + i];
                a0 = fmaf(e.x, zr[i].x, a0);
                a1 = fmaf(e.y, zr[i].y, a1);
                a2 = fmaf(e.z, zr[i].z, a2);
                a3 = fmaf(e.w, zr[i].w, a3);
            }
            float dot   = (a0 + a1) + (a2 + a3);
            float score = fmaf(-2.0f, dot, sesq[c]);   // ||e||^2 - 2 z.e
            if (score < best) { best = score; bk = cbase + c; }
        }
    }

    // Pack (score, index) -> monotone u64; atomicMin picks min score,
    // then min index on ties (matches argmin first-occurrence semantics).
    unsigned int sb = __float_as_uint(best);
    sb = (sb & 0x80000000u) ? ~sb : (sb | 0x80000000u);
    unsigned long long key = ((unsigned long long)sb << 32) | (unsigned)bk;
    atomicMin(&keys[n], key);
}

// ---------------------------------------------------------------------------
// Kernel 2: epilogue. 2 threads per row (halves of D).
// Gathers e_k, writes z_q_st, indices, loss partials, counts/dw atomics.
// grid = 512, block = 256.
// ---------------------------------------------------------------------------
__global__ __launch_bounds__(256) void vq_epilogue_kernel(
    const float* __restrict__ z, const float* __restrict__ emb,
    const unsigned long long* __restrict__ keys,
    float* __restrict__ out, float* __restrict__ counts,
    float* __restrict__ dw, float* __restrict__ loss_acc)
{
    const int tid = threadIdx.x;
    const int n   = blockIdx.x * 128 + (tid & 127);  // row
    const int h   = tid >> 7;                        // 0/1: which 32 dims
    const int b   = n >> 10;
    const int hw  = n & 1023;
    const int k   = (int)(keys[n] & 0xFFFFFFFFull);

    const float*  zb  = z   + ((size_t)(b * D + h * 32)) * HW + hw;
    float*        oq  = out + O_ZQ + ((size_t)(b * D + h * 32)) * HW + hw;
    const float4* ek4 = (const float4*)emb + (size_t)k * 16 + h * 8;

    float lacc = 0.f;
#pragma unroll
    for (int i = 0; i < 8; ++i) {
        float4 e = ek4[i];   // gather, L2-resident (embedding = 256 KB)
        float z0 = zb[(i * 4 + 0) * HW];
        float z1 = zb[(i * 4 + 1) * HW];
        float z2 = zb[(i * 4 + 2) * HW];
        float z3 = zb[(i * 4 + 3) * HW];
        // straight-through: z + (z_q - z), same op order as reference
        oq[(i * 4 + 0) * HW] = z0 + (e.x - z0);
        oq[(i * 4 + 1) * HW] = z1 + (e.y - z1);
        oq[(i * 4 + 2) * HW] = z2 + (e.z - z2);
        oq[(i * 4 + 3) * HW] = z3 + (e.w - z3);
        float d0 = z0 - e.x, d1 = z1 - e.y, d2 = z2 - e.z, d3 = z3 - e.w;
        lacc = fmaf(d0, d0, lacc);
        lacc = fmaf(d1, d1, lacc);
        lacc = fmaf(d2, d2, lacc);
        lacc = fmaf(d3, d3, lacc);
        const int dbase = k * D + h * 32 + i * 4;
        atomicAdd(&dw[dbase + 0], z0);
        atomicAdd(&dw[dbase + 1], z1);
        atomicAdd(&dw[dbase + 2], z2);
        atomicAdd(&dw[dbase + 3], z3);
    }

    if (h == 0) {
        out[O_IDX + n] = (float)k;
        atomicAdd(&counts[k], 1.0f);
    }

    // wave-level loss reduction (64 lanes), one atomic per wave
    for (int off = 32; off; off >>= 1) lacc += __shfl_down(lacc, off);
    if ((tid & 63) == 0) atomicAdd(loss_acc, lacc);
}

// ---------------------------------------------------------------------------
// Kernel 3: new_cluster_size, global n, loss finalization. 1 block x 1024.
// ---------------------------------------------------------------------------
__global__ __launch_bounds__(1024) void vq_ema_kernel(
    const float* __restrict__ cs, const float* __restrict__ counts,
    float* __restrict__ out, const float* __restrict__ loss_acc,
    float* __restrict__ n_val)
{
    __shared__ float red[16];
    const int k = threadIdx.x;
    float ncs = 0.99f * cs[k] + 0.01f * counts[k];
    out[O_NCS + k] = ncs;
    float s = ncs;
    for (int off = 32; off; off >>= 1) s += __shfl_down(s, off);
    if ((k & 63) == 0) red[k >> 6] = s;
    __syncthreads();
    if (k == 0) {
        float n = 0.f;
#pragma unroll
        for (int i = 0; i < 16; ++i) n += red[i];
        n_val[0] = n;
        out[O_LOSS] = 0.25f * loss_acc[0] / (float)NELEM;
    }
}

// ---------------------------------------------------------------------------
// Kernel 4: new_ema_w and new_embedding (elementwise). 64 blocks x 256.
// ---------------------------------------------------------------------------
__global__ __launch_bounds__(256) void vq_upd_kernel(
    const float* __restrict__ ema_w, const float* __restrict__ dw,
    const float* __restrict__ n_val, float* __restrict__ out)
{
    const int i = blockIdx.x * 256 + threadIdx.x;   // 0..16383 (float4 units)
    const int k = i >> 4;
    const float n  = n_val[0];
    const float ncs = out[O_NCS + k];               // written by vq_ema_kernel
    const float cs  = (ncs + 1e-5f) / (n + 0.01024f) * n;  // K*EPS = 0.01024
    const float4 w  = ((const float4*)ema_w)[i];
    const float4 dv = ((const float4*)dw)[i];
    float nw[4];
    nw[0] = 0.99f * w.x + 0.01f * dv.x;
    nw[1] = 0.99f * w.y + 0.01f * dv.y;
    nw[2] = 0.99f * w.z + 0.01f * dv.z;
    nw[3] = 0.99f * w.w + 0.01f * dv.w;
    const int base = i * 4;   // output regions are odd-offset: scalar stores
#pragma unroll
    for (int j = 0; j < 4; ++j) {
        out[O_EMAW + base + j] = nw[j];
        out[O_EMB  + base + j] = nw[j] / cs;
    }
}

// ---------------------------------------------------------------------------
extern "C" void kernel_launch(void* const* d_in, const int* in_sizes, int n_in,
                              void* d_out, int out_size, void* d_ws, size_t ws_size,
                              hipStream_t stream) {
    const float* z     = (const float*)d_in[0];
    const float* emb   = (const float*)d_in[1];
    const float* cs    = (const float*)d_in[2];
    const float* ema_w = (const float*)d_in[3];
    float* out = (float*)d_out;

    float* ws_f   = (float*)d_ws;
    float* counts = ws_f + WS_COUNTS;
    float* dw     = ws_f + WS_DW;
    float* lossa  = ws_f + WS_LOSS;
    float* n_val  = ws_f + WS_N;
    unsigned long long* keys =
        (unsigned long long*)((char*)d_ws + WS_KEYS_BYTES);

    // zero accumulators; 0xFF -> keys = ULLONG_MAX
    hipMemsetAsync(d_ws, 0, WS_ZERO_BYTES, stream);
    hipMemsetAsync((char*)d_ws + WS_KEYS_BYTES, 0xFF,
                   (size_t)NROWS * 8, stream);

    vq_dist_kernel<<<dim3(256, SPLITS), 256, 0, stream>>>(z, emb, keys);
    vq_epilogue_kernel<<<512, 256, 0, stream>>>(z, emb, keys, out, counts,
                                                dw, lossa);
    vq_ema_kernel<<<1, 1024, 0, stream>>>(cs, counts, out, lossa, n_val);
    vq_upd_kernel<<<64, 256, 0, stream>>>(ema_w, dw, n_val, out);
}

// Round 3
// 311.395 us; speedup vs baseline: 3.5763x; 3.5763x over previous
//
#include <hip/hip_runtime.h>
#include <stdint.h>

// Problem constants (fixed by reference setup_inputs)
#define D      64
#define K      1024
#define HW     1024          // H*W
#define NROWS  65536         // B*H*W
#define NELEM  (NROWS * D)

// Output layout (floats, concatenated in reference return order)
#define O_ZQ   0
#define O_LOSS 4194304
#define O_IDX  4194305
#define O_NCS  4259841
#define O_EMAW 4260865
#define O_EMB  4326401

// Workspace byte offsets relative to base b0 (zf optionally at 0)
#define WB_KEYS    0x00000    // 65536 i32
#define WB_BUCKET  0x40000    // 65536 i32
#define WB_ESQ     0x80000    // 1024 f32
#define WB_OFFS    0x81000    // 1024 u32
#define WB_CURSOR  0x82000    // 1024 u32
#define WB_COUNTS  0x83000    // 1024 u32   (memset 0)
#define WB_LOSSN   0x84000    // loss f32, n f32 (memset 0)
#define WB_END     0x84100
#define ZF_BYTES   0x1000000  // 65536*64 f32 = 16 MB

// ---------------------------------------------------------------------------
// Kernel 0: esq[k] = ||emb[k]||^2.  grid 16 x 64.
// ---------------------------------------------------------------------------
__global__ __launch_bounds__(64) void vq_esq_kernel(
    const float* __restrict__ emb, float* __restrict__ esq)
{
    const int k = blockIdx.x * 64 + threadIdx.x;
    const float4* e4 = (const float4*)emb + (size_t)k * 16;
    float a = 0.f;
#pragma unroll
    for (int i = 0; i < 16; ++i) {
        float4 e = e4[i];
        a += e.x * e.x + e.y * e.y + e.z * e.z + e.w * e.w;
    }
    esq[k] = a;
}

// ---------------------------------------------------------------------------
// Kernel 1: distance argmin, outer-product tiled.
// Block: 256 threads = 16 tx (code quads) x 16 ty (row quads).
// Tile: 64 rows x 1024 codes (16 chunks of 64).  grid = 1024 blocks.
// Writes keys[n] (int code) directly; counts via int atomics (hidden).
// ---------------------------------------------------------------------------
#define ES 68   // lds_e stride (floats): 16B-aligned rows

__global__ __launch_bounds__(256, 4) void vq_dist_kernel(
    const float* __restrict__ z, const float* __restrict__ emb,
    const float* __restrict__ esq, int* __restrict__ keys,
    unsigned* __restrict__ counts)
{
    __shared__ float lds_z[64 * 64];   // [d][row]  16 KB
    __shared__ float lds_e[64 * ES];   // [d][code] 17 KB

    const int tid = threadIdx.x;
    const int tx  = tid & 15;          // code quad
    const int ty  = tid >> 4;          // row quad
    const int n0  = blockIdx.x * 64;   // first row of tile (within one b)
    const int b   = n0 >> 10;
    const int hw0 = n0 & 1023;

    const float4* emb4 = (const float4*)emb;

    // ---- load z-tile: z[b][d][hw0..hw0+63] -> lds_z[d][r] (4 float4/thread)
    {
        const float* zb = z + (size_t)b * D * HW + hw0;
#pragma unroll
        for (int j = 0; j < 4; ++j) {
            int f4id = j * 256 + tid;          // 0..1023
            int d    = f4id >> 4;
            int r4   = f4id & 15;
            float4 v = *(const float4*)(zb + (size_t)d * HW + r4 * 4);
            *(float4*)&lds_z[d * 64 + r4 * 4] = v;
        }
    }

    // ---- prefetch e-chunk 0 into registers
    float4 pf[4];
#pragma unroll
    for (int j = 0; j < 4; ++j) {
        int f4id = j * 256 + tid;
        int c    = f4id >> 4;                  // 0..63
        int d4   = f4id & 15;
        pf[j] = emb4[(size_t)c * 16 + d4];
    }

    float bv[4] = {INFINITY, INFINITY, INFINITY, INFINITY};
    int   bi[4] = {0, 0, 0, 0};

    for (int ch = 0; ch < 16; ++ch) {
        const int cbase = ch * 64;

        // store prefetched chunk (transposed) into lds_e
#pragma unroll
        for (int j = 0; j < 4; ++j) {
            int f4id = j * 256 + tid;
            int c    = f4id >> 4;
            int d4   = f4id & 15;
            lds_e[(d4 * 4 + 0) * ES + c] = pf[j].x;
            lds_e[(d4 * 4 + 1) * ES + c] = pf[j].y;
            lds_e[(d4 * 4 + 2) * ES + c] = pf[j].z;
            lds_e[(d4 * 4 + 3) * ES + c] = pf[j].w;
        }
        // prefetch next chunk
        if (ch < 15) {
#pragma unroll
            for (int j = 0; j < 4; ++j) {
                int f4id = j * 256 + tid;
                int c    = f4id >> 4;
                int d4   = f4id & 15;
                pf[j] = emb4[(size_t)(cbase + 64 + c) * 16 + d4];
            }
        }
        __syncthreads();   // lds_e (and, first iter, lds_z) visible

        float acc[4][4] = {{0.f,0.f,0.f,0.f},{0.f,0.f,0.f,0.f},
                           {0.f,0.f,0.f,0.f},{0.f,0.f,0.f,0.f}};
#pragma unroll 8
        for (int dd = 0; dd < 64; ++dd) {
            float4 zq = *(const float4*)&lds_z[dd * 64 + (ty << 2)];
            float4 eq = *(const float4*)&lds_e[dd * ES + (tx << 2)];
            acc[0][0] = fmaf(zq.x, eq.x, acc[0][0]);
            acc[0][1] = fmaf(zq.x, eq.y, acc[0][1]);
            acc[0][2] = fmaf(zq.x, eq.z, acc[0][2]);
            acc[0][3] = fmaf(zq.x, eq.w, acc[0][3]);
            acc[1][0] = fmaf(zq.y, eq.x, acc[1][0]);
            acc[1][1] = fmaf(zq.y, eq.y, acc[1][1]);
            acc[1][2] = fmaf(zq.y, eq.z, acc[1][2]);
            acc[1][3] = fmaf(zq.y, eq.w, acc[1][3]);
            acc[2][0] = fmaf(zq.z, eq.x, acc[2][0]);
            acc[2][1] = fmaf(zq.z, eq.y, acc[2][1]);
            acc[2][2] = fmaf(zq.z, eq.z, acc[2][2]);
            acc[2][3] = fmaf(zq.z, eq.w, acc[2][3]);
            acc[3][0] = fmaf(zq.w, eq.x, acc[3][0]);
            acc[3][1] = fmaf(zq.w, eq.y, acc[3][1]);
            acc[3][2] = fmaf(zq.w, eq.z, acc[3][2]);
            acc[3][3] = fmaf(zq.w, eq.w, acc[3][3]);
        }

        // scores + per-row argmin (first-min tie-break everywhere)
        float4 esqv = *(const float4*)&esq[cbase + (tx << 2)];
        float esqa[4] = {esqv.x, esqv.y, esqv.z, esqv.w};
#pragma unroll
        for (int i = 0; i < 4; ++i) {
            float v  = fmaf(-2.0f, acc[i][0], esqa[0]);
            int   ix = cbase + (tx << 2);
#pragma unroll
            for (int u = 1; u < 4; ++u) {
                float s = fmaf(-2.0f, acc[i][u], esqa[u]);
                if (s < v) { v = s; ix = cbase + (tx << 2) + u; }
            }
            // reduce across the 16 tx lanes (same ty -> same 16-lane group)
#pragma unroll
            for (int m = 1; m < 16; m <<= 1) {
                float ov = __shfl_xor(v, m);
                int   oi = __shfl_xor(ix, m);
                if (ov < v || (ov == v && oi < ix)) { v = ov; ix = oi; }
            }
            if (v < bv[i]) { bv[i] = v; bi[i] = ix; }   // chunks ascending
        }
        __syncthreads();   // compute done before next chunk's store
    }

    if (tx == 0) {
#pragma unroll
        for (int i = 0; i < 4; ++i) {
            keys[n0 + (ty << 2) + i] = bi[i];
            atomicAdd(&counts[bi[i]], 1u);
        }
    }
}

// ---------------------------------------------------------------------------
// Kernel 2: scan.  1 block x 1024.  offs = exclusive scan of counts;
// cursor = offs; ncs + n_val.
// ---------------------------------------------------------------------------
__global__ __launch_bounds__(1024) void vq_scan_kernel(
    const unsigned* __restrict__ counts, const float* __restrict__ cs,
    unsigned* __restrict__ offs, unsigned* __restrict__ cursor,
    float* __restrict__ out, float* __restrict__ n_val)
{
    __shared__ unsigned wtot[16], wbase[16];
    __shared__ float    fred[16];
    const int k    = threadIdx.x;
    const int lane = k & 63;
    const int w    = k >> 6;

    unsigned c = counts[k];
    unsigned v = c;
#pragma unroll
    for (int off = 1; off < 64; off <<= 1) {
        unsigned t = __shfl_up(v, off);
        if (lane >= off) v += t;
    }
    if (lane == 63) wtot[w] = v;

    float ncs = 0.99f * cs[k] + 0.01f * (float)c;
    out[O_NCS + k] = ncs;
    float s = ncs;
#pragma unroll
    for (int off = 32; off; off >>= 1) s += __shfl_down(s, off);
    if (lane == 0) fred[w] = s;

    __syncthreads();
    if (k == 0) {
        unsigned base = 0;
        float    nt   = 0.f;
#pragma unroll
        for (int i = 0; i < 16; ++i) {
            wbase[i] = base;
            base += wtot[i];
            nt   += fred[i];
        }
        n_val[0] = nt;
    }
    __syncthreads();
    unsigned o = wbase[w] + (v - c);
    offs[k]   = o;
    cursor[k] = o;
}

// ---------------------------------------------------------------------------
// Kernel 3: epilogue.  2 threads/row.  z_q_st, zf (transposed), indices,
// loss partials, bucket scatter.  grid 512 x 256.
// ---------------------------------------------------------------------------
template <bool ZF>
__global__ __launch_bounds__(256) void vq_epilogue_kernel(
    const float* __restrict__ z, const float* __restrict__ emb,
    const int* __restrict__ keys, float* __restrict__ out,
    float* __restrict__ zf, unsigned* __restrict__ cursor,
    int* __restrict__ bucket, float* __restrict__ loss_acc)
{
    const int tid = threadIdx.x;
    const int n   = blockIdx.x * 128 + (tid & 127);
    const int h   = tid >> 7;
    const int b   = n >> 10;
    const int hw  = n & 1023;
    const int k   = keys[n];

    const float*  zb  = z   + ((size_t)(b * D + h * 32)) * HW + hw;
    float*        oq  = out + O_ZQ + ((size_t)(b * D + h * 32)) * HW + hw;
    const float4* ek4 = (const float4*)emb + (size_t)k * 16 + h * 8;
    float4*       zfp = ZF ? (float4*)(zf + (size_t)n * 64 + h * 32) : nullptr;

    float lacc = 0.f;
#pragma unroll
    for (int i = 0; i < 8; ++i) {
        float4 e = ek4[i];
        float z0 = zb[(i * 4 + 0) * HW];
        float z1 = zb[(i * 4 + 1) * HW];
        float z2 = zb[(i * 4 + 2) * HW];
        float z3 = zb[(i * 4 + 3) * HW];
        oq[(i * 4 + 0) * HW] = z0 + (e.x - z0);
        oq[(i * 4 + 1) * HW] = z1 + (e.y - z1);
        oq[(i * 4 + 2) * HW] = z2 + (e.z - z2);
        oq[(i * 4 + 3) * HW] = z3 + (e.w - z3);
        if (ZF) zfp[i] = make_float4(z0, z1, z2, z3);
        float d0 = z0 - e.x, d1 = z1 - e.y, d2 = z2 - e.z, d3 = z3 - e.w;
        lacc = fmaf(d0, d0, lacc);
        lacc = fmaf(d1, d1, lacc);
        lacc = fmaf(d2, d2, lacc);
        lacc = fmaf(d3, d3, lacc);
    }

    if (h == 0) {
        out[O_IDX + n] = (float)k;
        unsigned pos = atomicAdd(&cursor[k], 1u);
        bucket[pos]  = n;
    }

    for (int off = 32; off; off >>= 1) lacc += __shfl_down(lacc, off);
    if ((tid & 63) == 0) atomicAdd(loss_acc, lacc);
}

// ---------------------------------------------------------------------------
// Kernel 4: fused dw + EMA update.  grid 1024 x 256 (block per code).
// ---------------------------------------------------------------------------
template <bool ZF>
__global__ __launch_bounds__(256) void vq_upd_kernel(
    const float* __restrict__ z, const float* __restrict__ zf,
    const int* __restrict__ bucket, const unsigned* __restrict__ offs,
    const unsigned* __restrict__ counts, const float* __restrict__ ema_w,
    const float* __restrict__ n_val, const float* __restrict__ loss_acc,
    float* __restrict__ out)
{
    __shared__ float red[4][64];
    const int k   = blockIdx.x;
    const int tid = threadIdx.x;
    const int d   = tid & 63;
    const int q   = tid >> 6;
    const unsigned off = offs[k];
    const unsigned cnt = counts[k];

    auto zload = [&](int r) -> float {
        if (ZF) return zf[(size_t)r * 64 + d];
        return z[(size_t)(r >> 10) * (D * HW) + (size_t)d * HW + (r & 1023)];
    };

    float acc = 0.f;
    unsigned j = q;
    for (; j + 12 < cnt; j += 16) {
        int r0 = bucket[off + j];
        int r1 = bucket[off + j + 4];
        int r2 = bucket[off + j + 8];
        int r3 = bucket[off + j + 12];
        float v0 = zload(r0), v1 = zload(r1), v2 = zload(r2), v3 = zload(r3);
        acc += v0; acc += v1; acc += v2; acc += v3;
    }
    for (; j < cnt; j += 4) acc += zload(bucket[off + j]);

    red[q][d] = acc;
    __syncthreads();
    if (q == 0) {
        float dw = red[0][d] + red[1][d] + red[2][d] + red[3][d];
        float nw = 0.99f * ema_w[k * 64 + d] + 0.01f * dw;
        out[O_EMAW + k * 64 + d] = nw;
        float n   = n_val[0];
        float ncs = out[O_NCS + k];
        float csv = (ncs + 1e-5f) / (n + 1024e-5f) * n;
        out[O_EMB + k * 64 + d] = nw / csv;
    }
    if (k == 0 && tid == 0)
        out[O_LOSS] = 0.25f * loss_acc[0] / (float)NELEM;
}

// ---------------------------------------------------------------------------
extern "C" void kernel_launch(void* const* d_in, const int* in_sizes, int n_in,
                              void* d_out, int out_size, void* d_ws, size_t ws_size,
                              hipStream_t stream) {
    const float* z     = (const float*)d_in[0];
    const float* emb   = (const float*)d_in[1];
    const float* cs    = (const float*)d_in[2];
    const float* ema_w = (const float*)d_in[3];
    float* out = (float*)d_out;

    const bool use_zf = ws_size >= (size_t)(ZF_BYTES + WB_END + 256);
    char* base = (char*)d_ws + (use_zf ? ZF_BYTES : 0);

    float*    zf      = (float*)d_ws;                 // only valid if use_zf
    int*      keys    = (int*)(base + WB_KEYS);
    int*      bucket  = (int*)(base + WB_BUCKET);
    float*    esq     = (float*)(base + WB_ESQ);
    unsigned* offs    = (unsigned*)(base + WB_OFFS);
    unsigned* cursor  = (unsigned*)(base + WB_CURSOR);
    unsigned* counts  = (unsigned*)(base + WB_COUNTS);
    float*    lossa   = (float*)(base + WB_LOSSN);
    float*    n_val   = lossa + 1;

    // zero counts + loss/n in one memset
    hipMemsetAsync(base + WB_COUNTS, 0, 0x1100, stream);

    vq_esq_kernel<<<16, 64, 0, stream>>>(emb, esq);
    vq_dist_kernel<<<1024, 256, 0, stream>>>(z, emb, esq, keys, counts);
    vq_scan_kernel<<<1, 1024, 0, stream>>>(counts, cs, offs, cursor, out, n_val);
    if (use_zf) {
        vq_epilogue_kernel<true><<<512, 256, 0, stream>>>(z, emb, keys, out, zf,
                                                          cursor, bucket, lossa);
        vq_upd_kernel<true><<<1024, 256, 0, stream>>>(z, zf, bucket, offs, counts,
                                                      ema_w, n_val, lossa, out);
    } else {
        vq_epilogue_kernel<false><<<512, 256, 0, stream>>>(z, emb, keys, out, zf,
                                                           cursor, bucket, lossa);
        vq_upd_kernel<false><<<1024, 256, 0, stream>>>(z, zf, bucket, offs, counts,
                                                       ema_w, n_val, lossa, out);
    }
}

// Round 4
// 251.135 us; speedup vs baseline: 4.4345x; 1.2399x over previous
//
#include <hip/hip_runtime.h>
#include <stdint.h>

typedef unsigned short ushort;
typedef __attribute__((ext_vector_type(8)))  short bfrag;   // 8 bf16 = 4 VGPR
typedef __attribute__((ext_vector_type(16))) float f32x16;  // MFMA 32x32 acc

#define D      64
#define K      1024
#define HW     1024
#define NROWS  65536
#define NELEM  (NROWS * D)
#define BAND   0.01f

// Output layout (floats, reference return order)
#define O_ZQ   0
#define O_LOSS 4194304
#define O_IDX  4194305
#define O_NCS  4259841
#define O_EMAW 4260865
#define O_EMB  4326401

// Workspace layout (bytes)
#define WB_KEYS   0x000000   // 64K i32
#define WB_BUCKET 0x040000   // 64K i32
#define WB_EH     0x080000   // 1024x64 u16
#define WB_EL     0x0A0000
#define WB_ESQ    0x0C0000   // 1024 f32
#define WB_OFFS   0x0C1000
#define WB_CURSOR 0x0C2000
#define WB_COUNTS 0x0C3000   // memset 0 (0x2000 covers counts..rlist start)
#define WB_LOSSN  0x0C4000   // loss, n, rcnt
#define WB_RLIST  0x0C5000   // 64K i32
#define WB_ZH     0x105000   // 65536x64 u16 = 8MB (tier 1 only)
#define WB_END_T1 0x905000

__device__ __forceinline__ unsigned bf16r(float x) {   // RNE f32->bf16 bits
    unsigned u = __float_as_uint(x);
    return (u + 0x7FFFu + ((u >> 16) & 1u)) >> 16;
}
__device__ __forceinline__ float bf16f(unsigned h) {
    return __uint_as_float(h << 16);
}

// ---------------------------------------------------------------------------
// Kernel 0: per-code prep: esq (fp32 exact) + bf16 hi/lo split of embedding.
// grid 16 x 64 (thread = code).
// ---------------------------------------------------------------------------
__global__ __launch_bounds__(64) void vq_prep_e(
    const float* __restrict__ emb, ushort* __restrict__ eh,
    ushort* __restrict__ el, float* __restrict__ esq)
{
    const int k = blockIdx.x * 64 + threadIdx.x;
    const float* er = emb + (size_t)k * 64;
    float a = 0.f;
    for (int d = 0; d < 64; ++d) {
        float v = er[d];
        a = fmaf(v, v, a);
        unsigned hh = bf16r(v);
        float rem = v - bf16f(hh);
        unsigned ll = bf16r(rem);
        eh[k * 64 + d] = (ushort)hh;
        el[k * 64 + d] = (ushort)ll;
    }
    esq[k] = a;
}

// ---------------------------------------------------------------------------
// Kernel 1: MFMA distance argmin (3-product bf16 split) + top-2 certification.
// block 256 (4 waves x 32 rows = 128 rows/block), grid 512.
// LDS: z hi/lo [128][64] bf16 XOR-swizzled (16B units), e-chunk (64 codes)
// staged in MFMA-fragment order (conflict-free b128 reads), esq staged.
// ---------------------------------------------------------------------------
__global__ __launch_bounds__(256, 3) void vq_dist_kernel(
    const float* __restrict__ z, const short* __restrict__ eh_g,
    const short* __restrict__ el_g, const float* __restrict__ esq_g,
    int* __restrict__ keys, unsigned* __restrict__ counts,
    unsigned* __restrict__ rcnt, int* __restrict__ rlist,
    ushort* __restrict__ zh_g, int dump)
{
    __shared__ __align__(16) short zh_lds[128 * 64];  // 16 KB
    __shared__ __align__(16) short zl_lds[128 * 64];  // 16 KB
    __shared__ __align__(16) short eh_lds[64 * 64];   // 8 KB (frag order)
    __shared__ __align__(16) short el_lds[64 * 64];   // 8 KB
    __shared__ float esq_lds[1024];                   // 4 KB

    const int tid  = threadIdx.x;
    const int lane = tid & 63;
    const int wave = tid >> 6;
    const int col  = lane & 31;
    const int h    = lane >> 5;
    const int n0   = blockIdx.x * 128;
    const int b    = n0 >> 10;
    const int hw0  = n0 & 1023;

    // ---- Phase A: stage z -> LDS (bf16 hi/lo, swizzled). 1024 tasks.
    for (int it = 0; it < 4; ++it) {
        int task = it * 256 + tid;
        int row  = task & 127;          // lanes -> consecutive hw (coalesced)
        int kq   = task >> 7;           // k-octet 0..7
        const float* zp = z + (size_t)b * 65536 + (size_t)(kq * 8) * 1024 + hw0 + row;
        bfrag vh, vl;
#pragma unroll
        for (int m = 0; m < 8; ++m) {
            float v = zp[m * 1024];
            unsigned hh = bf16r(v);
            float rem = v - bf16f(hh);
            vh[m] = (short)hh;
            vl[m] = (short)bf16r(rem);
        }
        int unit = kq ^ (row & 7);      // 16B-unit XOR swizzle
        *(bfrag*)&zh_lds[row * 64 + unit * 8] = vh;
        *(bfrag*)&zl_lds[row * 64 + unit * 8] = vl;
    }
    for (int it = 0; it < 4; ++it) {
        int t = it * 256 + tid;
        esq_lds[t] = esq_g[t];
    }
    __syncthreads();

    // ---- A-frags for K=64 (once; reused over all 1024 codes)
    const int wrow = wave * 32 + col;   // this lane's A-row in the 128-tile
    bfrag zhA[4], zlA[4];
#pragma unroll
    for (int j = 0; j < 4; ++j) {
        int kq = j * 2 + h;             // k = j*16 + h*8 + 0..7
        int unit = kq ^ (wrow & 7);
        zhA[j] = *(const bfrag*)&zh_lds[wrow * 64 + unit * 8];
        zlA[j] = *(const bfrag*)&zl_lds[wrow * 64 + unit * 8];
    }

    // ---- dump zh to global [n][64] for the upd kernel (tier 1)
    if (dump) {
        for (int it = 0; it < 4; ++it) {
            int task = it * 256 + tid;
            int row  = task >> 3;
            int kq   = task & 7;
            int unit = kq ^ (row & 7);
            uint4 v = *(const uint4*)&zh_lds[row * 64 + unit * 8];
            *(uint4*)&zh_g[(size_t)(n0 + row) * 64 + kq * 8] = v;
        }
    }

    float t1s[16], t2s[16];
    unsigned t1c[16];
#pragma unroll
    for (int i = 0; i < 16; ++i) { t1s[i] = INFINITY; t2s[i] = INFINITY; t1c[i] = 0; }

    // ---- e-chunk prefetch (64 codes/chunk, 16 chunks)
    bfrag pfh[2], pfl[2];
    auto loadE = [&](int cb) {
#pragma unroll
        for (int q = 0; q < 2; ++q) {
            int u = q * 256 + tid;      // 512 units/split
            int code = u >> 3, m = u & 7;
            pfh[q] = *(const bfrag*)&eh_g[(size_t)(cb + code) * 64 + m * 8];
            pfl[q] = *(const bfrag*)&el_g[(size_t)(cb + code) * 64 + m * 8];
        }
    };
    auto writeE = [&]() {
#pragma unroll
        for (int q = 0; q < 2; ++q) {
            int u = q * 256 + tid;
            int code = u >> 3, m = u & 7;
            int unit = ((code >> 5) * 4 + (m >> 1)) * 64 +
                       ((((m & 1) << 5) | (code & 31)) ^ (m & 7));
            *(bfrag*)&eh_lds[unit * 8] = pfh[q];
            *(bfrag*)&el_lds[unit * 8] = pfl[q];
        }
    };

    loadE(0);
    for (int ch = 0; ch < 16; ++ch) {
        const int cb = ch * 64;
        __syncthreads();                 // previous chunk's compute done
        writeE();
        __syncthreads();                 // chunk visible
        if (ch < 15) loadE(cb + 64);     // next chunk in flight during compute

#pragma unroll
        for (int t = 0; t < 2; ++t) {
            bfrag ehB[4], elB[4];
#pragma unroll
            for (int j = 0; j < 4; ++j) {
                int m = j * 2 + h;
                int unit = (t * 4 + j) * 64 + (((h << 5) | col) ^ (m & 7));
                ehB[j] = *(const bfrag*)&eh_lds[unit * 8];
                elB[j] = *(const bfrag*)&el_lds[unit * 8];
            }
            f32x16 acc1 = {}, acc2 = {};
#pragma unroll
            for (int j = 0; j < 4; ++j)
                acc1 = __builtin_amdgcn_mfma_f32_32x32x16_bf16(zhA[j], ehB[j], acc1, 0, 0, 0);
#pragma unroll
            for (int j = 0; j < 4; ++j)
                acc2 = __builtin_amdgcn_mfma_f32_32x32x16_bf16(zhA[j], elB[j], acc2, 0, 0, 0);
#pragma unroll
            for (int j = 0; j < 4; ++j)
                acc2 = __builtin_amdgcn_mfma_f32_32x32x16_bf16(zlA[j], ehB[j], acc2, 0, 0, 0);

            const float esqv = esq_lds[cb + t * 32 + col];
            const unsigned ccode = cb + t * 32 + col;
#pragma unroll
            for (int i = 0; i < 16; ++i) {
                float s = fmaf(-2.f, acc1[i], esqv);
                s = fmaf(-2.f, acc2[i], s);
                float mx = fmaxf(s, t1s[i]);        // old t1
                t2s[i] = fminf(t2s[i], mx);
                bool lt = s < t1s[i];
                t1s[i] = fminf(t1s[i], s);
                t1c[i] = lt ? ccode : t1c[i];
            }
        }
    }

    // ---- per-row cross-lane argmin (32 cols), C/D row = (i&3)+8*(i>>2)+4h
#pragma unroll
    for (int i = 0; i < 16; ++i) {
        float v = t1s[i], w = t2s[i];
        int   c = (int)t1c[i];
#pragma unroll
        for (int m = 1; m < 32; m <<= 1) {
            float ov = __shfl_xor(v, m);
            int   oc = __shfl_xor(c, m);
            float ow = __shfl_xor(w, m);
            float mx = fmaxf(v, ov);
            w = fminf(fminf(w, ow), mx);
            bool take = (ov < v) || (ov == v && oc < c);
            v = take ? ov : v;
            c = take ? oc : c;
        }
        if ((lane & 31) == 0) {
            int row = (i & 3) + ((i >> 2) << 3) + (h << 2);
            int n = n0 + wave * 32 + row;
            keys[n] = c;
            atomicAdd(&counts[c], 1u);
            if (w - v < BAND) {              // uncertified: exact rescore later
                unsigned p = atomicAdd(rcnt, 1u);
                rlist[p] = n;
            }
        }
    }
}

// ---------------------------------------------------------------------------
// Kernel 2: exact fp32 rescore of uncertified rows (rare). grid 96 x 256.
// ---------------------------------------------------------------------------
__global__ __launch_bounds__(256) void vq_rescore(
    const float* __restrict__ z, const float* __restrict__ emb,
    const float* __restrict__ esq, const unsigned* __restrict__ rcnt,
    const int* __restrict__ rlist, int* __restrict__ keys,
    unsigned* __restrict__ counts)
{
    __shared__ float zrow[64];
    __shared__ float rs[4];
    __shared__ int   rc[4];
    const int tid = threadIdx.x;
    const unsigned cnt = rcnt[0];

    for (unsigned i = blockIdx.x; i < cnt; i += gridDim.x) {
        const int n = rlist[i];
        const int b = n >> 10, hw = n & 1023;
        __syncthreads();
        if (tid < 64) zrow[tid] = z[(size_t)b * 65536 + (size_t)tid * 1024 + hw];
        __syncthreads();

        float best = INFINITY; int bc = 0;
        for (int rep = 0; rep < 4; ++rep) {
            int code = rep * 256 + tid;
            const float4* er = (const float4*)(emb + (size_t)code * 64);
            float a0 = 0.f, a1 = 0.f, a2 = 0.f, a3 = 0.f;
#pragma unroll
            for (int q = 0; q < 16; ++q) {
                float4 e = er[q];
                a0 = fmaf(zrow[q * 4 + 0], e.x, a0);
                a1 = fmaf(zrow[q * 4 + 1], e.y, a1);
                a2 = fmaf(zrow[q * 4 + 2], e.z, a2);
                a3 = fmaf(zrow[q * 4 + 3], e.w, a3);
            }
            float s = fmaf(-2.f, (a0 + a1) + (a2 + a3), esq[code]);
            if (s < best || (s == best && code < bc)) { best = s; bc = code; }
        }
        for (int m = 1; m < 64; m <<= 1) {
            float ov = __shfl_xor(best, m);
            int   oc = __shfl_xor(bc, m);
            bool take = (ov < best) || (ov == best && oc < bc);
            best = take ? ov : best;
            bc   = take ? oc : bc;
        }
        if ((tid & 63) == 0) { rs[tid >> 6] = best; rc[tid >> 6] = bc; }
        __syncthreads();
        if (tid == 0) {
            float fb = rs[0]; int fc = rc[0];
#pragma unroll
            for (int q = 1; q < 4; ++q) {
                bool take = (rs[q] < fb) || (rs[q] == fb && rc[q] < fc);
                fb = take ? rs[q] : fb;
                fc = take ? rc[q] : fc;
            }
            int old = keys[n];
            if (fc != old) {
                atomicAdd(&counts[old], (unsigned)-1);
                atomicAdd(&counts[fc], 1u);
                keys[n] = fc;
            }
        }
    }
}

// ---------------------------------------------------------------------------
// Kernel 3: scan. 1 block x 1024.
// ---------------------------------------------------------------------------
__global__ __launch_bounds__(1024) void vq_scan_kernel(
    const unsigned* __restrict__ counts, const float* __restrict__ cs,
    unsigned* __restrict__ offs, unsigned* __restrict__ cursor,
    float* __restrict__ out, float* __restrict__ n_val)
{
    __shared__ unsigned wtot[16], wbase[16];
    __shared__ float    fred[16];
    const int k    = threadIdx.x;
    const int lane = k & 63;
    const int w    = k >> 6;

    unsigned c = counts[k];
    unsigned v = c;
#pragma unroll
    for (int off = 1; off < 64; off <<= 1) {
        unsigned t = __shfl_up(v, off);
        if (lane >= off) v += t;
    }
    if (lane == 63) wtot[w] = v;

    float ncs = 0.99f * cs[k] + 0.01f * (float)c;
    out[O_NCS + k] = ncs;
    float s = ncs;
#pragma unroll
    for (int off = 32; off; off >>= 1) s += __shfl_down(s, off);
    if (lane == 0) fred[w] = s;

    __syncthreads();
    if (k == 0) {
        unsigned base = 0;
        float nt = 0.f;
#pragma unroll
        for (int i = 0; i < 16; ++i) {
            wbase[i] = base;
            base += wtot[i];
            nt += fred[i];
        }
        n_val[0] = nt;
    }
    __syncthreads();
    unsigned o = wbase[w] + (v - c);
    offs[k]   = o;
    cursor[k] = o;
}

// ---------------------------------------------------------------------------
// Kernel 4: epilogue. z_q_st, indices, loss partials, bucket scatter.
// ---------------------------------------------------------------------------
__global__ __launch_bounds__(256) void vq_epilogue_kernel(
    const float* __restrict__ z, const float* __restrict__ emb,
    const int* __restrict__ keys, float* __restrict__ out,
    unsigned* __restrict__ cursor, int* __restrict__ bucket,
    float* __restrict__ loss_acc)
{
    const int tid = threadIdx.x;
    const int n   = blockIdx.x * 128 + (tid & 127);
    const int h   = tid >> 7;
    const int b   = n >> 10;
    const int hw  = n & 1023;
    const int k   = keys[n];

    const float*  zb  = z   + ((size_t)(b * D + h * 32)) * HW + hw;
    float*        oq  = out + O_ZQ + ((size_t)(b * D + h * 32)) * HW + hw;
    const float4* ek4 = (const float4*)emb + (size_t)k * 16 + h * 8;

    float lacc = 0.f;
#pragma unroll
    for (int i = 0; i < 8; ++i) {
        float4 e = ek4[i];
        float z0 = zb[(i * 4 + 0) * HW];
        float z1 = zb[(i * 4 + 1) * HW];
        float z2 = zb[(i * 4 + 2) * HW];
        float z3 = zb[(i * 4 + 3) * HW];
        oq[(i * 4 + 0) * HW] = z0 + (e.x - z0);
        oq[(i * 4 + 1) * HW] = z1 + (e.y - z1);
        oq[(i * 4 + 2) * HW] = z2 + (e.z - z2);
        oq[(i * 4 + 3) * HW] = z3 + (e.w - z3);
        float d0 = z0 - e.x, d1 = z1 - e.y, d2 = z2 - e.z, d3 = z3 - e.w;
        lacc = fmaf(d0, d0, lacc);
        lacc = fmaf(d1, d1, lacc);
        lacc = fmaf(d2, d2, lacc);
        lacc = fmaf(d3, d3, lacc);
    }

    if (h == 0) {
        out[O_IDX + n] = (float)k;
        unsigned pos = atomicAdd(&cursor[k], 1u);
        bucket[pos]  = n;
    }

    for (int off = 32; off; off >>= 1) lacc += __shfl_down(lacc, off);
    if ((tid & 63) == 0) atomicAdd(loss_acc, lacc);
}

// ---------------------------------------------------------------------------
// Kernel 5: dw + EMA update. block per code. MODE1: coalesced zh reads.
// ---------------------------------------------------------------------------
template <int MODE>
__global__ __launch_bounds__(256) void vq_upd_kernel(
    const float* __restrict__ z, const ushort* __restrict__ zh,
    const int* __restrict__ bucket, const unsigned* __restrict__ offs,
    const unsigned* __restrict__ counts, const float* __restrict__ ema_w,
    const float* __restrict__ n_val, const float* __restrict__ loss_acc,
    float* __restrict__ out)
{
    __shared__ float red[4][64];
    const int k   = blockIdx.x;
    const int tid = threadIdx.x;
    const int d   = tid & 63;
    const int q   = tid >> 6;
    const unsigned off = offs[k];
    const unsigned cnt = counts[k];

    auto zload = [&](int r) -> float {
        if (MODE == 1)
            return __uint_as_float((unsigned)zh[(size_t)r * 64 + d] << 16);
        return z[(size_t)(r >> 10) * (D * HW) + (size_t)d * HW + (r & 1023)];
    };

    float acc = 0.f;
    unsigned j = q;
    for (; j + 12 < cnt; j += 16) {
        int r0 = bucket[off + j];
        int r1 = bucket[off + j + 4];
        int r2 = bucket[off + j + 8];
        int r3 = bucket[off + j + 12];
        acc += zload(r0); acc += zload(r1); acc += zload(r2); acc += zload(r3);
    }
    for (; j < cnt; j += 4) acc += zload(bucket[off + j]);

    red[q][d] = acc;
    __syncthreads();
    if (q == 0) {
        float dw = red[0][d] + red[1][d] + red[2][d] + red[3][d];
        float nw = 0.99f * ema_w[k * 64 + d] + 0.01f * dw;
        out[O_EMAW + k * 64 + d] = nw;
        float n   = n_val[0];
        float ncs = out[O_NCS + k];
        float csv = (ncs + 1e-5f) / (n + 1024e-5f) * n;
        out[O_EMB + k * 64 + d] = nw / csv;
    }
    if (k == 0 && tid == 0)
        out[O_LOSS] = 0.25f * loss_acc[0] / (float)NELEM;
}

// ---------------------------------------------------------------------------
extern "C" void kernel_launch(void* const* d_in, const int* in_sizes, int n_in,
                              void* d_out, int out_size, void* d_ws, size_t ws_size,
                              hipStream_t stream) {
    const float* z     = (const float*)d_in[0];
    const float* emb   = (const float*)d_in[1];
    const float* cs    = (const float*)d_in[2];
    const float* ema_w = (const float*)d_in[3];
    float* out = (float*)d_out;

    char* W = (char*)d_ws;
    int*      keys   = (int*)(W + WB_KEYS);
    int*      bucket = (int*)(W + WB_BUCKET);
    short*    eh_g   = (short*)(W + WB_EH);
    short*    el_g   = (short*)(W + WB_EL);
    float*    esq    = (float*)(W + WB_ESQ);
    unsigned* offs   = (unsigned*)(W + WB_OFFS);
    unsigned* cursor = (unsigned*)(W + WB_CURSOR);
    unsigned* counts = (unsigned*)(W + WB_COUNTS);
    float*    lossa  = (float*)(W + WB_LOSSN);
    float*    n_val  = lossa + 1;
    unsigned* rcnt   = (unsigned*)(W + WB_LOSSN + 8);
    int*      rlist  = (int*)(W + WB_RLIST);
    ushort*   zh_g   = (ushort*)(W + WB_ZH);

    const int dump = ws_size >= (size_t)WB_END_T1 ? 1 : 0;

    hipMemsetAsync(W + WB_COUNTS, 0, 0x2000, stream);   // counts + loss/n/rcnt

    vq_prep_e<<<16, 64, 0, stream>>>(emb, (ushort*)eh_g, (ushort*)el_g, esq);
    vq_dist_kernel<<<512, 256, 0, stream>>>(z, eh_g, el_g, esq, keys, counts,
                                            rcnt, rlist, zh_g, dump);
    vq_rescore<<<96, 256, 0, stream>>>(z, emb, esq, rcnt, rlist, keys, counts);
    vq_scan_kernel<<<1, 1024, 0, stream>>>(counts, cs, offs, cursor, out, n_val);
    vq_epilogue_kernel<<<512, 256, 0, stream>>>(z, emb, keys, out, cursor,
                                                bucket, lossa);
    if (dump)
        vq_upd_kernel<1><<<1024, 256, 0, stream>>>(z, zh_g, bucket, offs, counts,
                                                   ema_w, n_val, lossa, out);
    else
        vq_upd_kernel<0><<<1024, 256, 0, stream>>>(z, zh_g, bucket, offs, counts,
                                                   ema_w, n_val, lossa, out);
}

// Round 5
// 219.739 us; speedup vs baseline: 5.0681x; 1.1429x over previous
//
#include <hip/hip_runtime.h>
#include <stdint.h>

typedef unsigned short ushort;
typedef __attribute__((ext_vector_type(8)))  short bfrag;   // 8 bf16 = 4 VGPR
typedef __attribute__((ext_vector_type(16))) float f32x16;  // MFMA 32x32 acc

#define D      64
#define K      1024
#define HW     1024
#define NROWS  65536
#define NELEM  (NROWS * D)
#define BAND   0.01f

// Output layout (floats, reference return order)
#define O_ZQ   0
#define O_LOSS 4194304
#define O_IDX  4194305
#define O_NCS  4259841
#define O_EMAW 4260865
#define O_EMB  4326401

// Workspace layout (bytes) — total 0x85000 = 532 KB (ws proven >= ~790 KB)
#define WB_EH     0x00000   // 1024x64 u16 = 128K
#define WB_EL     0x20000   // 128K
#define WB_ESQ    0x40000   // 1024 f32
#define WB_OFFS   0x41000
#define WB_CURSOR 0x42000
#define WB_COUNTS 0x43000   // memset 0
#define WB_LOSSN  0x44000   // loss f32, n f32, rcnt u32 (memset 0)
#define WB_RLIST  0x45000   // 65536 i32 = 256K

__device__ __forceinline__ unsigned bf16r(float x) {   // RNE f32->bf16 bits
    unsigned u = __float_as_uint(x);
    return (u + 0x7FFFu + ((u >> 16) & 1u)) >> 16;
}
__device__ __forceinline__ float bf16f(unsigned h) {
    return __uint_as_float(h << 16);
}

// ---------------------------------------------------------------------------
// Kernel 0: wave per code: esq (fp32 exact) + plain bf16 hi/lo split of emb.
// grid 1024 x 64.
// ---------------------------------------------------------------------------
__global__ __launch_bounds__(64) void vq_prep_e(
    const float* __restrict__ emb, ushort* __restrict__ eh,
    ushort* __restrict__ el, float* __restrict__ esq)
{
    const int k = blockIdx.x;
    const int d = threadIdx.x;
    float v = emb[k * 64 + d];
    unsigned hh = bf16r(v);
    float rem = v - bf16f(hh);
    eh[k * 64 + d] = (ushort)hh;
    el[k * 64 + d] = (ushort)bf16r(rem);
    float a = v * v;
#pragma unroll
    for (int off = 32; off; off >>= 1) a += __shfl_xor(a, off);
    if (d == 0) esq[k] = a;
}

// ---------------------------------------------------------------------------
// Kernel 1: MFMA distance argmin. 256 thr (4 waves x 32 rows), grid 512.
// z pre-scaled by -2 in bf16 split; esq folded into accumulator init;
// top-2 via fmed3; e-chunk LDS double-buffered (1 barrier/chunk).
// ---------------------------------------------------------------------------
__global__ __launch_bounds__(256, 2) void vq_dist_kernel(
    const float* __restrict__ z, const short* __restrict__ eh_g,
    const short* __restrict__ el_g, const float* __restrict__ esq_g,
    float* __restrict__ out, unsigned* __restrict__ counts,
    unsigned* __restrict__ rcnt, int* __restrict__ rlist)
{
    __shared__ __align__(16) short zh_lds[128 * 64];      // 16 KB
    __shared__ __align__(16) short zl_lds[128 * 64];      // 16 KB
    __shared__ __align__(16) short eh_lds[2][64 * 64];    // 16 KB
    __shared__ __align__(16) short el_lds[2][64 * 64];    // 16 KB
    __shared__ float esq_lds[1024];                       // 4 KB

    const int tid  = threadIdx.x;
    const int lane = tid & 63;
    const int wave = tid >> 6;
    const int col  = lane & 31;
    const int h    = lane >> 5;
    const int n0   = blockIdx.x * 128;
    const int b    = n0 >> 10;
    const int hw0  = n0 & 1023;

    // ---- stage z -> LDS as bf16 hi/lo of (-2*z), XOR-swizzled 16B units
    for (int it = 0; it < 4; ++it) {
        int task = it * 256 + tid;
        int row  = task & 127;
        int kq   = task >> 7;
        const float* zp = z + (size_t)b * 65536 + (size_t)(kq * 8) * 1024 + hw0 + row;
        bfrag vh, vl;
#pragma unroll
        for (int m = 0; m < 8; ++m) {
            float t = -2.0f * zp[m * 1024];
            unsigned hh = bf16r(t);
            float rem = t - bf16f(hh);
            vh[m] = (short)hh;
            vl[m] = (short)bf16r(rem);
        }
        int unit = kq ^ (row & 7);
        *(bfrag*)&zh_lds[row * 64 + unit * 8] = vh;
        *(bfrag*)&zl_lds[row * 64 + unit * 8] = vl;
    }
    for (int it = 0; it < 4; ++it) {
        int t = it * 256 + tid;
        esq_lds[t] = esq_g[t];
    }

    // ---- e-chunk staging helpers (64 codes/chunk, verified frag-order map)
    bfrag pfh[2], pfl[2];
    auto loadE = [&](int cb) {
#pragma unroll
        for (int q = 0; q < 2; ++q) {
            int u = q * 256 + tid;
            int code = u >> 3, m = u & 7;
            pfh[q] = *(const bfrag*)&eh_g[(size_t)(cb + code) * 64 + m * 8];
            pfl[q] = *(const bfrag*)&el_g[(size_t)(cb + code) * 64 + m * 8];
        }
    };
    auto writeE = [&](int buf) {
#pragma unroll
        for (int q = 0; q < 2; ++q) {
            int u = q * 256 + tid;
            int code = u >> 3, m = u & 7;
            int unit = ((code >> 5) * 4 + (m >> 1)) * 64 +
                       ((((m & 1) << 5) | (code & 31)) ^ (m & 7));
            *(bfrag*)&eh_lds[buf][unit * 8] = pfh[q];
            *(bfrag*)&el_lds[buf][unit * 8] = pfl[q];
        }
    };

    loadE(0);
    writeE(0);
    loadE(64);
    __syncthreads();    // z staging + esq + e-buf0 visible

    // ---- A-frags (scaled -2z), reused over all 1024 codes
    const int wrow = wave * 32 + col;
    bfrag zhA[4], zlA[4];
#pragma unroll
    for (int j = 0; j < 4; ++j) {
        int kq = j * 2 + h;
        int unit = kq ^ (wrow & 7);
        zhA[j] = *(const bfrag*)&zh_lds[wrow * 64 + unit * 8];
        zlA[j] = *(const bfrag*)&zl_lds[wrow * 64 + unit * 8];
    }

    float t1s[16], t2s[16];
    unsigned t1c[16];
#pragma unroll
    for (int i = 0; i < 16; ++i) { t1s[i] = INFINITY; t2s[i] = INFINITY; t1c[i] = 0; }

    for (int ch = 0; ch < 16; ++ch) {
        const int cb  = ch * 64;
        const int buf = ch & 1;

#pragma unroll
        for (int t = 0; t < 2; ++t) {
            const int ccode = cb + t * 32 + col;
            const float esqv = esq_lds[ccode];
            bfrag ehB[4], elB[4];
#pragma unroll
            for (int j = 0; j < 4; ++j) {
                int m = j * 2 + h;
                int unit = (t * 4 + j) * 64 + (((h << 5) | col) ^ (m & 7));
                ehB[j] = *(const bfrag*)&eh_lds[buf][unit * 8];
                elB[j] = *(const bfrag*)&el_lds[buf][unit * 8];
            }
            f32x16 acc;
#pragma unroll
            for (int i = 0; i < 16; ++i) acc[i] = esqv;   // fold ||e||^2
#pragma unroll
            for (int j = 0; j < 4; ++j)
                acc = __builtin_amdgcn_mfma_f32_32x32x16_bf16(zhA[j], ehB[j], acc, 0, 0, 0);
#pragma unroll
            for (int j = 0; j < 4; ++j)
                acc = __builtin_amdgcn_mfma_f32_32x32x16_bf16(zhA[j], elB[j], acc, 0, 0, 0);
#pragma unroll
            for (int j = 0; j < 4; ++j)
                acc = __builtin_amdgcn_mfma_f32_32x32x16_bf16(zlA[j], ehB[j], acc, 0, 0, 0);

#pragma unroll
            for (int i = 0; i < 16; ++i) {
                float s = acc[i];                               // full score
                t2s[i] = __builtin_amdgcn_fmed3f(t1s[i], t2s[i], s);  // runner-up
                bool lt = s < t1s[i];
                t1s[i] = fminf(t1s[i], s);
                t1c[i] = lt ? (unsigned)ccode : t1c[i];
            }
        }

        if (ch < 15) {
            writeE(buf ^ 1);            // pf holds chunk ch+1 (other buffer)
            if (ch < 14) loadE(cb + 128);
        }
        __syncthreads();
    }

    // ---- per-row cross-lane argmin + top-2 gap, C/D row = (i&3)+8*(i>>2)+4h
#pragma unroll
    for (int i = 0; i < 16; ++i) {
        float v = t1s[i], w = t2s[i];
        int   c = (int)t1c[i];
#pragma unroll
        for (int m = 1; m < 32; m <<= 1) {
            float ov = __shfl_xor(v, m);
            int   oc = __shfl_xor(c, m);
            float ow = __shfl_xor(w, m);
            float mx = fmaxf(v, ov);
            w = fminf(fminf(w, ow), mx);
            bool take = (ov < v) || (ov == v && oc < c);
            v = take ? ov : v;
            c = take ? oc : c;
        }
        if ((lane & 31) == 0) {
            int row = (i & 3) + ((i >> 2) << 3) + (h << 2);
            int n = n0 + wave * 32 + row;
            out[O_IDX + n] = (float)c;
            atomicAdd(&counts[c], 1u);
            if (w - v < BAND) {
                unsigned p = atomicAdd(rcnt, 1u);
                rlist[p] = n;
            }
        }
    }
}

// ---------------------------------------------------------------------------
// Kernel 2: exact fp32 rescore of uncertified rows. grid 512 x 256.
// ---------------------------------------------------------------------------
__global__ __launch_bounds__(256) void vq_rescore(
    const float* __restrict__ z, const float* __restrict__ emb,
    const float* __restrict__ esq, const unsigned* __restrict__ rcnt,
    const int* __restrict__ rlist, float* __restrict__ out,
    unsigned* __restrict__ counts)
{
    __shared__ float zrow[64];
    __shared__ float rs[4];
    __shared__ int   rc[4];
    const int tid = threadIdx.x;
    const unsigned cnt = rcnt[0];

    for (unsigned i = blockIdx.x; i < cnt; i += gridDim.x) {
        const int n = rlist[i];
        const int b = n >> 10, hw = n & 1023;
        __syncthreads();
        if (tid < 64) zrow[tid] = z[(size_t)b * 65536 + (size_t)tid * 1024 + hw];
        __syncthreads();

        float best = INFINITY; int bc = 0;
        for (int rep = 0; rep < 4; ++rep) {
            int code = rep * 256 + tid;
            const float4* er = (const float4*)(emb + (size_t)code * 64);
            float a0 = 0.f, a1 = 0.f, a2 = 0.f, a3 = 0.f;
#pragma unroll
            for (int q = 0; q < 16; ++q) {
                float4 e = er[q];
                a0 = fmaf(zrow[q * 4 + 0], e.x, a0);
                a1 = fmaf(zrow[q * 4 + 1], e.y, a1);
                a2 = fmaf(zrow[q * 4 + 2], e.z, a2);
                a3 = fmaf(zrow[q * 4 + 3], e.w, a3);
            }
            float s = fmaf(-2.f, (a0 + a1) + (a2 + a3), esq[code]);
            if (s < best || (s == best && code < bc)) { best = s; bc = code; }
        }
        for (int m = 1; m < 64; m <<= 1) {
            float ov = __shfl_xor(best, m);
            int   oc = __shfl_xor(bc, m);
            bool take = (ov < best) || (ov == best && oc < bc);
            best = take ? ov : best;
            bc   = take ? oc : bc;
        }
        if ((tid & 63) == 0) { rs[tid >> 6] = best; rc[tid >> 6] = bc; }
        __syncthreads();
        if (tid == 0) {
            float fb = rs[0]; int fc = rc[0];
#pragma unroll
            for (int q = 1; q < 4; ++q) {
                bool take = (rs[q] < fb) || (rs[q] == fb && rc[q] < fc);
                fb = take ? rs[q] : fb;
                fc = take ? rc[q] : fc;
            }
            int old = (int)out[O_IDX + n];
            if (fc != old) {
                atomicAdd(&counts[old], (unsigned)-1);
                atomicAdd(&counts[fc], 1u);
                out[O_IDX + n] = (float)fc;
            }
        }
    }
}

// ---------------------------------------------------------------------------
// Kernel 3: scan. 1 block x 1024.
// ---------------------------------------------------------------------------
__global__ __launch_bounds__(1024) void vq_scan_kernel(
    const unsigned* __restrict__ counts, const float* __restrict__ cs,
    unsigned* __restrict__ offs, unsigned* __restrict__ cursor,
    float* __restrict__ out, float* __restrict__ n_val)
{
    __shared__ unsigned wtot[16], wbase[16];
    __shared__ float    fred[16];
    const int k    = threadIdx.x;
    const int lane = k & 63;
    const int w    = k >> 6;

    unsigned c = counts[k];
    unsigned v = c;
#pragma unroll
    for (int off = 1; off < 64; off <<= 1) {
        unsigned t = __shfl_up(v, off);
        if (lane >= off) v += t;
    }
    if (lane == 63) wtot[w] = v;

    float ncs = 0.99f * cs[k] + 0.01f * (float)c;
    out[O_NCS + k] = ncs;
    float s = ncs;
#pragma unroll
    for (int off = 32; off; off >>= 1) s += __shfl_down(s, off);
    if (lane == 0) fred[w] = s;

    __syncthreads();
    if (k == 0) {
        unsigned base = 0;
        float nt = 0.f;
#pragma unroll
        for (int i = 0; i < 16; ++i) {
            wbase[i] = base;
            base += wtot[i];
            nt += fred[i];
        }
        n_val[0] = nt;
    }
    __syncthreads();
    unsigned o = wbase[w] + (v - c);
    offs[k]   = o;
    cursor[k] = o;
}

// ---------------------------------------------------------------------------
// Kernel 4: scatter epilogue. Thread per row: counting-sort z rows into the
// O_ZQ output region (scratch until zq_writer), loss partials. grid 256x256.
// ---------------------------------------------------------------------------
__global__ __launch_bounds__(256) void vq_scatter_kernel(
    const float* __restrict__ z, const float* __restrict__ emb,
    float* __restrict__ out, unsigned* __restrict__ cursor,
    float* __restrict__ loss_acc)
{
    const int tid = threadIdx.x;
    const int n   = blockIdx.x * 256 + tid;
    const int b   = n >> 10;
    const int hw  = n & 1023;
    const int k   = (int)out[O_IDX + n];

    const unsigned pos = atomicAdd(&cursor[k], 1u);
    const float*  zb  = z + (size_t)b * 65536 + hw;
    const float4* ek4 = (const float4*)emb + (size_t)k * 16;
    float* dst = out + O_ZQ + (size_t)pos * 64;

    float lacc = 0.f;
#pragma unroll
    for (int i = 0; i < 16; ++i) {
        float4 e = ek4[i];
        float z0 = zb[(i * 4 + 0) * 1024];
        float z1 = zb[(i * 4 + 1) * 1024];
        float z2 = zb[(i * 4 + 2) * 1024];
        float z3 = zb[(i * 4 + 3) * 1024];
        *(float4*)&dst[i * 4] = make_float4(z0, z1, z2, z3);
        float d0 = z0 - e.x, d1 = z1 - e.y, d2 = z2 - e.z, d3 = z3 - e.w;
        lacc = fmaf(d0, d0, lacc);
        lacc = fmaf(d1, d1, lacc);
        lacc = fmaf(d2, d2, lacc);
        lacc = fmaf(d3, d3, lacc);
    }

    for (int off = 32; off; off >>= 1) lacc += __shfl_down(lacc, off);
    if ((tid & 63) == 0) atomicAdd(loss_acc, lacc);
}

// ---------------------------------------------------------------------------
// Kernel 5: dw + EMA update. Block per code; rows contiguous in sorted zf
// (= O_ZQ region), fully coalesced. grid 1024 x 256.
// ---------------------------------------------------------------------------
__global__ __launch_bounds__(256) void vq_upd_kernel(
    const float* __restrict__ zf, const unsigned* __restrict__ offs,
    const unsigned* __restrict__ counts, const float* __restrict__ ema_w,
    const float* __restrict__ n_val, const float* __restrict__ loss_acc,
    float* __restrict__ out)
{
    __shared__ float red[4][64];
    const int k   = blockIdx.x;
    const int tid = threadIdx.x;
    const int d   = tid & 63;
    const int q   = tid >> 6;
    const unsigned off = offs[k];
    const unsigned cnt = counts[k];

    float acc = 0.f;
    unsigned j = q;
    for (; j + 12 < cnt; j += 16) {
        float v0 = zf[(size_t)(off + j)      * 64 + d];
        float v1 = zf[(size_t)(off + j + 4)  * 64 + d];
        float v2 = zf[(size_t)(off + j + 8)  * 64 + d];
        float v3 = zf[(size_t)(off + j + 12) * 64 + d];
        acc += v0; acc += v1; acc += v2; acc += v3;
    }
    for (; j < cnt; j += 4) acc += zf[(size_t)(off + j) * 64 + d];

    red[q][d] = acc;
    __syncthreads();
    if (q == 0) {
        float dw = red[0][d] + red[1][d] + red[2][d] + red[3][d];
        float nw = 0.99f * ema_w[k * 64 + d] + 0.01f * dw;
        out[O_EMAW + k * 64 + d] = nw;
        float n   = n_val[0];
        float ncs = out[O_NCS + k];
        float csv = (ncs + 1e-5f) / (n + 1024e-5f) * n;
        out[O_EMB + k * 64 + d] = nw / csv;
    }
    if (k == 0 && tid == 0)
        out[O_LOSS] = 0.25f * loss_acc[0] / (float)NELEM;
}

// ---------------------------------------------------------------------------
// Kernel 6: final z_q_st writer (overwrites the O_ZQ scratch). grid 512x256.
// ---------------------------------------------------------------------------
__global__ __launch_bounds__(256) void vq_zqwrite_kernel(
    const float* __restrict__ z, const float* __restrict__ emb,
    float* __restrict__ out)
{
    const int tid = threadIdx.x;
    const int n   = blockIdx.x * 128 + (tid & 127);
    const int h   = tid >> 7;
    const int b   = n >> 10;
    const int hw  = n & 1023;
    const int k   = (int)out[O_IDX + n];

    const float*  zb  = z   + ((size_t)(b * D + h * 32)) * HW + hw;
    float*        oq  = out + O_ZQ + ((size_t)(b * D + h * 32)) * HW + hw;
    const float4* ek4 = (const float4*)emb + (size_t)k * 16 + h * 8;

#pragma unroll
    for (int i = 0; i < 8; ++i) {
        float4 e = ek4[i];
        float z0 = zb[(i * 4 + 0) * HW];
        float z1 = zb[(i * 4 + 1) * HW];
        float z2 = zb[(i * 4 + 2) * HW];
        float z3 = zb[(i * 4 + 3) * HW];
        oq[(i * 4 + 0) * HW] = z0 + (e.x - z0);
        oq[(i * 4 + 1) * HW] = z1 + (e.y - z1);
        oq[(i * 4 + 2) * HW] = z2 + (e.z - z2);
        oq[(i * 4 + 3) * HW] = z3 + (e.w - z3);
    }
}

// ---------------------------------------------------------------------------
extern "C" void kernel_launch(void* const* d_in, const int* in_sizes, int n_in,
                              void* d_out, int out_size, void* d_ws, size_t ws_size,
                              hipStream_t stream) {
    const float* z     = (const float*)d_in[0];
    const float* emb   = (const float*)d_in[1];
    const float* cs    = (const float*)d_in[2];
    const float* ema_w = (const float*)d_in[3];
    float* out = (float*)d_out;

    char* W = (char*)d_ws;
    short*    eh_g   = (short*)(W + WB_EH);
    short*    el_g   = (short*)(W + WB_EL);
    float*    esq    = (float*)(W + WB_ESQ);
    unsigned* offs   = (unsigned*)(W + WB_OFFS);
    unsigned* cursor = (unsigned*)(W + WB_CURSOR);
    unsigned* counts = (unsigned*)(W + WB_COUNTS);
    float*    lossa  = (float*)(W + WB_LOSSN);
    float*    n_val  = lossa + 1;
    unsigned* rcnt   = (unsigned*)(W + WB_LOSSN + 8);
    int*      rlist  = (int*)(W + WB_RLIST);

    hipMemsetAsync(W + WB_COUNTS, 0, 0x2000, stream);   // counts + loss/n/rcnt

    vq_prep_e<<<1024, 64, 0, stream>>>(emb, (ushort*)eh_g, (ushort*)el_g, esq);
    vq_dist_kernel<<<512, 256, 0, stream>>>(z, eh_g, el_g, esq, out, counts,
                                            rcnt, rlist);
    vq_rescore<<<512, 256, 0, stream>>>(z, emb, esq, rcnt, rlist, out, counts);
    vq_scan_kernel<<<1, 1024, 0, stream>>>(counts, cs, offs, cursor, out, n_val);
    vq_scatter_kernel<<<256, 256, 0, stream>>>(z, emb, out, cursor, lossa);
    vq_upd_kernel<<<1024, 256, 0, stream>>>(out + O_ZQ, offs, counts, ema_w,
                                            n_val, lossa, out);
    vq_zqwrite_kernel<<<512, 256, 0, stream>>>(z, emb, out);
}

// Round 6
// 218.464 us; speedup vs baseline: 5.0976x; 1.0058x over previous
//
#include <hip/hip_runtime.h>
#include <stdint.h>

typedef unsigned short ushort;
typedef __attribute__((ext_vector_type(8)))  short bfrag;   // 8 bf16 = 4 VGPR
typedef __attribute__((ext_vector_type(16))) float f32x16;  // MFMA 32x32 acc

#define D      64
#define K      1024
#define HW     1024
#define NROWS  65536
#define NELEM  (NROWS * D)
#define BAND   0.01f

// Output layout (floats, reference return order)
#define O_ZQ   0
#define O_LOSS 4194304
#define O_IDX  4194305
#define O_NCS  4259841
#define O_EMAW 4260865
#define O_EMB  4326401

// Workspace layout (bytes)
#define WB_EH     0x00000   // 1024x64 u16 = 128K
#define WB_EL     0x20000   // 128K
#define WB_ESQ    0x40000   // 1024 f32
#define WB_OFFS   0x41000
#define WB_CURSOR 0x42000
#define WB_COUNTS 0x43000   // zeroed by prep_e
#define WB_LOSSN  0x44000   // loss f32, n f32, rcnt u32 (zeroed by prep_e)
#define WB_RLIST  0x45000   // 65536 i32 = 256K -> ends 0x85000
#define WB_ZF     0x100000  // 16 MB sorted rows (fused path only)
#define WS_NEED_FUSED (0x100000 + 0x1000000)

__device__ __forceinline__ unsigned bf16r(float x) {   // RNE f32->bf16 bits
    unsigned u = __float_as_uint(x);
    return (u + 0x7FFFu + ((u >> 16) & 1u)) >> 16;
}
__device__ __forceinline__ float bf16f(unsigned h) {
    return __uint_as_float(h << 16);
}

// ---------------------------------------------------------------------------
// Kernel 0: wave-per-code esq + bf16 hi/lo split; block 0 zeroes control blk.
// grid 256 x 256 (4 waves/block).
// ---------------------------------------------------------------------------
__global__ __launch_bounds__(256) void vq_prep_e(
    const float* __restrict__ emb, ushort* __restrict__ eh,
    ushort* __restrict__ el, float* __restrict__ esq,
    unsigned* __restrict__ zero_region)
{
    const int tid = threadIdx.x;
    if (blockIdx.x == 0) {
#pragma unroll
        for (int i = 0; i < 8; ++i) zero_region[i * 256 + tid] = 0u;  // 8 KB
    }
    const int k = blockIdx.x * 4 + (tid >> 6);
    const int d = tid & 63;
    float v = emb[k * 64 + d];
    unsigned hh = bf16r(v);
    float rem = v - bf16f(hh);
    eh[k * 64 + d] = (ushort)hh;
    el[k * 64 + d] = (ushort)bf16r(rem);
    float a = v * v;
#pragma unroll
    for (int off = 32; off; off >>= 1) a += __shfl_xor(a, off);
    if (d == 0) esq[k] = a;
}

// ---------------------------------------------------------------------------
// Kernel 1: MFMA distance argmin. 256 thr (4 waves x 32 rows), grid 512.
// Two independent MFMA chains (code-groups t0/t1) per chunk; setprio around
// the MFMA cluster; e-chunk LDS double-buffered (1 barrier/chunk).
// ---------------------------------------------------------------------------
__global__ __launch_bounds__(256, 2) void vq_dist_kernel(
    const float* __restrict__ z, const short* __restrict__ eh_g,
    const short* __restrict__ el_g, const float* __restrict__ esq_g,
    float* __restrict__ out, unsigned* __restrict__ counts,
    unsigned* __restrict__ rcnt, int* __restrict__ rlist)
{
    __shared__ __align__(16) short zh_lds[128 * 64];      // 16 KB
    __shared__ __align__(16) short zl_lds[128 * 64];      // 16 KB
    __shared__ __align__(16) short eh_lds[2][64 * 64];    // 16 KB
    __shared__ __align__(16) short el_lds[2][64 * 64];    // 16 KB
    __shared__ float esq_lds[1024];                       // 4 KB

    const int tid  = threadIdx.x;
    const int lane = tid & 63;
    const int wave = tid >> 6;
    const int col  = lane & 31;
    const int h    = lane >> 5;
    const int n0   = blockIdx.x * 128;
    const int b    = n0 >> 10;
    const int hw0  = n0 & 1023;

    // ---- stage z -> LDS as bf16 hi/lo of (-2*z), XOR-swizzled 16B units
    for (int it = 0; it < 4; ++it) {
        int task = it * 256 + tid;
        int row  = task & 127;
        int kq   = task >> 7;
        const float* zp = z + (size_t)b * 65536 + (size_t)(kq * 8) * 1024 + hw0 + row;
        bfrag vh, vl;
#pragma unroll
        for (int m = 0; m < 8; ++m) {
            float t = -2.0f * zp[m * 1024];
            unsigned hh = bf16r(t);
            float rem = t - bf16f(hh);
            vh[m] = (short)hh;
            vl[m] = (short)bf16r(rem);
        }
        int unit = kq ^ (row & 7);
        *(bfrag*)&zh_lds[row * 64 + unit * 8] = vh;
        *(bfrag*)&zl_lds[row * 64 + unit * 8] = vl;
    }
    for (int it = 0; it < 4; ++it) {
        int t = it * 256 + tid;
        esq_lds[t] = esq_g[t];
    }

    // ---- e-chunk staging helpers (64 codes/chunk)
    bfrag pfh[2], pfl[2];
    auto loadE = [&](int cb) {
#pragma unroll
        for (int q = 0; q < 2; ++q) {
            int u = q * 256 + tid;
            int code = u >> 3, m = u & 7;
            pfh[q] = *(const bfrag*)&eh_g[(size_t)(cb + code) * 64 + m * 8];
            pfl[q] = *(const bfrag*)&el_g[(size_t)(cb + code) * 64 + m * 8];
        }
    };
    auto writeE = [&](int buf) {
#pragma unroll
        for (int q = 0; q < 2; ++q) {
            int u = q * 256 + tid;
            int code = u >> 3, m = u & 7;
            int unit = ((code >> 5) * 4 + (m >> 1)) * 64 +
                       ((((m & 1) << 5) | (code & 31)) ^ (m & 7));
            *(bfrag*)&eh_lds[buf][unit * 8] = pfh[q];
            *(bfrag*)&el_lds[buf][unit * 8] = pfl[q];
        }
    };

    loadE(0);
    writeE(0);
    loadE(64);
    __syncthreads();    // z staging + esq + e-buf0 visible

    // ---- A-frags (scaled -2z), reused over all 1024 codes
    const int wrow = wave * 32 + col;
    bfrag zhA[4], zlA[4];
#pragma unroll
    for (int j = 0; j < 4; ++j) {
        int kq = j * 2 + h;
        int unit = kq ^ (wrow & 7);
        zhA[j] = *(const bfrag*)&zh_lds[wrow * 64 + unit * 8];
        zlA[j] = *(const bfrag*)&zl_lds[wrow * 64 + unit * 8];
    }

    float t1s[16], t2s[16];
    unsigned t1c[16];
#pragma unroll
    for (int i = 0; i < 16; ++i) { t1s[i] = INFINITY; t2s[i] = INFINITY; t1c[i] = 0; }

    for (int ch = 0; ch < 16; ++ch) {
        const int cb  = ch * 64;
        const int buf = ch & 1;

        // load BOTH code-groups' B-frags up front (16 ds_read_b128)
        bfrag ehB0[4], elB0[4], ehB1[4], elB1[4];
#pragma unroll
        for (int j = 0; j < 4; ++j) {
            int m = j * 2 + h;
            int sw = (((h << 5) | col) ^ (m & 7));
            ehB0[j] = *(const bfrag*)&eh_lds[buf][(j * 64 + sw) * 8];
            elB0[j] = *(const bfrag*)&el_lds[buf][(j * 64 + sw) * 8];
            ehB1[j] = *(const bfrag*)&eh_lds[buf][((4 + j) * 64 + sw) * 8];
            elB1[j] = *(const bfrag*)&el_lds[buf][((4 + j) * 64 + sw) * 8];
        }
        const float esq0 = esq_lds[cb + col];
        const float esq1 = esq_lds[cb + 32 + col];
        const unsigned c0 = cb + col;
        const unsigned c1 = cb + 32 + col;

        f32x16 acc0, acc1;
#pragma unroll
        for (int i = 0; i < 16; ++i) { acc0[i] = esq0; acc1[i] = esq1; }

        __builtin_amdgcn_s_setprio(1);
#pragma unroll
        for (int j = 0; j < 4; ++j) {
            acc0 = __builtin_amdgcn_mfma_f32_32x32x16_bf16(zhA[j], ehB0[j], acc0, 0, 0, 0);
            acc1 = __builtin_amdgcn_mfma_f32_32x32x16_bf16(zhA[j], ehB1[j], acc1, 0, 0, 0);
        }
#pragma unroll
        for (int j = 0; j < 4; ++j) {
            acc0 = __builtin_amdgcn_mfma_f32_32x32x16_bf16(zhA[j], elB0[j], acc0, 0, 0, 0);
            acc1 = __builtin_amdgcn_mfma_f32_32x32x16_bf16(zhA[j], elB1[j], acc1, 0, 0, 0);
        }
#pragma unroll
        for (int j = 0; j < 4; ++j) {
            acc0 = __builtin_amdgcn_mfma_f32_32x32x16_bf16(zlA[j], ehB0[j], acc0, 0, 0, 0);
            acc1 = __builtin_amdgcn_mfma_f32_32x32x16_bf16(zlA[j], ehB1[j], acc1, 0, 0, 0);
        }
        __builtin_amdgcn_s_setprio(0);

        // refill the other buffer while scores update
        if (ch < 15) {
            writeE(buf ^ 1);
            if (ch < 14) loadE(cb + 128);
        }

#pragma unroll
        for (int i = 0; i < 16; ++i) {
            float s0 = acc0[i];
            t2s[i] = __builtin_amdgcn_fmed3f(t1s[i], t2s[i], s0);
            bool lt0 = s0 < t1s[i];
            t1s[i] = fminf(t1s[i], s0);
            t1c[i] = lt0 ? c0 : t1c[i];
            float s1 = acc1[i];
            t2s[i] = __builtin_amdgcn_fmed3f(t1s[i], t2s[i], s1);
            bool lt1 = s1 < t1s[i];
            t1s[i] = fminf(t1s[i], s1);
            t1c[i] = lt1 ? c1 : t1c[i];
        }
        __syncthreads();
    }

    // ---- per-row cross-lane argmin + top-2 gap, C/D row = (i&3)+8*(i>>2)+4h
#pragma unroll
    for (int i = 0; i < 16; ++i) {
        float v = t1s[i], w = t2s[i];
        int   c = (int)t1c[i];
#pragma unroll
        for (int m = 1; m < 32; m <<= 1) {
            float ov = __shfl_xor(v, m);
            int   oc = __shfl_xor(c, m);
            float ow = __shfl_xor(w, m);
            float mx = fmaxf(v, ov);
            w = fminf(fminf(w, ow), mx);
            bool take = (ov < v) || (ov == v && oc < c);
            v = take ? ov : v;
            c = take ? oc : c;
        }
        if ((lane & 31) == 0) {
            int row = (i & 3) + ((i >> 2) << 3) + (h << 2);
            int n = n0 + wave * 32 + row;
            out[O_IDX + n] = (float)c;
            atomicAdd(&counts[c], 1u);
            if (w - v < BAND) {
                unsigned p = atomicAdd(rcnt, 1u);
                rlist[p] = n;
            }
        }
    }
}

// ---------------------------------------------------------------------------
// Kernel 2: exact fp32 rescore of uncertified rows. grid 128 x 256.
// ---------------------------------------------------------------------------
__global__ __launch_bounds__(256) void vq_rescore(
    const float* __restrict__ z, const float* __restrict__ emb,
    const float* __restrict__ esq, const unsigned* __restrict__ rcnt,
    const int* __restrict__ rlist, float* __restrict__ out,
    unsigned* __restrict__ counts)
{
    __shared__ float zrow[64];
    __shared__ float rs[4];
    __shared__ int   rc[4];
    const int tid = threadIdx.x;
    const unsigned cnt = rcnt[0];

    for (unsigned i = blockIdx.x; i < cnt; i += gridDim.x) {
        const int n = rlist[i];
        const int b = n >> 10, hw = n & 1023;
        __syncthreads();
        if (tid < 64) zrow[tid] = z[(size_t)b * 65536 + (size_t)tid * 1024 + hw];
        __syncthreads();

        float best = INFINITY; int bc = 0;
        for (int rep = 0; rep < 4; ++rep) {
            int code = rep * 256 + tid;
            const float4* er = (const float4*)(emb + (size_t)code * 64);
            float a0 = 0.f, a1 = 0.f, a2 = 0.f, a3 = 0.f;
#pragma unroll
            for (int q = 0; q < 16; ++q) {
                float4 e = er[q];
                a0 = fmaf(zrow[q * 4 + 0], e.x, a0);
                a1 = fmaf(zrow[q * 4 + 1], e.y, a1);
                a2 = fmaf(zrow[q * 4 + 2], e.z, a2);
                a3 = fmaf(zrow[q * 4 + 3], e.w, a3);
            }
            float s = fmaf(-2.f, (a0 + a1) + (a2 + a3), esq[code]);
            if (s < best || (s == best && code < bc)) { best = s; bc = code; }
        }
        for (int m = 1; m < 64; m <<= 1) {
            float ov = __shfl_xor(best, m);
            int   oc = __shfl_xor(bc, m);
            bool take = (ov < best) || (ov == best && oc < bc);
            best = take ? ov : best;
            bc   = take ? oc : bc;
        }
        if ((tid & 63) == 0) { rs[tid >> 6] = best; rc[tid >> 6] = bc; }
        __syncthreads();
        if (tid == 0) {
            float fb = rs[0]; int fc = rc[0];
#pragma unroll
            for (int q = 1; q < 4; ++q) {
                bool take = (rs[q] < fb) || (rs[q] == fb && rc[q] < fc);
                fb = take ? rs[q] : fb;
                fc = take ? rc[q] : fc;
            }
            int old = (int)out[O_IDX + n];
            if (fc != old) {
                atomicAdd(&counts[old], (unsigned)-1);
                atomicAdd(&counts[fc], 1u);
                out[O_IDX + n] = (float)fc;
            }
        }
    }
}

// ---------------------------------------------------------------------------
// Kernel 3: scan. 1 block x 1024.
// ---------------------------------------------------------------------------
__global__ __launch_bounds__(1024) void vq_scan_kernel(
    const unsigned* __restrict__ counts, const float* __restrict__ cs,
    unsigned* __restrict__ offs, unsigned* __restrict__ cursor,
    float* __restrict__ out, float* __restrict__ n_val)
{
    __shared__ unsigned wtot[16], wbase[16];
    __shared__ float    fred[16];
    const int k    = threadIdx.x;
    const int lane = k & 63;
    const int w    = k >> 6;

    unsigned c = counts[k];
    unsigned v = c;
#pragma unroll
    for (int off = 1; off < 64; off <<= 1) {
        unsigned t = __shfl_up(v, off);
        if (lane >= off) v += t;
    }
    if (lane == 63) wtot[w] = v;

    float ncs = 0.99f * cs[k] + 0.01f * (float)c;
    out[O_NCS + k] = ncs;
    float s = ncs;
#pragma unroll
    for (int off = 32; off; off >>= 1) s += __shfl_down(s, off);
    if (lane == 0) fred[w] = s;

    __syncthreads();
    if (k == 0) {
        unsigned base = 0;
        float nt = 0.f;
#pragma unroll
        for (int i = 0; i < 16; ++i) {
            wbase[i] = base;
            base += wtot[i];
            nt += fred[i];
        }
        n_val[0] = nt;
    }
    __syncthreads();
    unsigned o = wbase[w] + (v - c);
    offs[k]   = o;
    cursor[k] = o;
}

// ---------------------------------------------------------------------------
// Kernel 4a (fused, ws >= 17.1MB): one z pass -> z_q_st + sorted zf(ws) +
// loss. grid 256 x 256.
// ---------------------------------------------------------------------------
__global__ __launch_bounds__(256) void vq_scatter_fused(
    const float* __restrict__ z, const float* __restrict__ emb,
    float* __restrict__ out, float* __restrict__ zf,
    unsigned* __restrict__ cursor, float* __restrict__ loss_acc)
{
    const int tid = threadIdx.x;
    const int n   = blockIdx.x * 256 + tid;
    const int b   = n >> 10;
    const int hw  = n & 1023;
    const int k   = (int)out[O_IDX + n];

    const unsigned pos = atomicAdd(&cursor[k], 1u);
    const float*  zb  = z   + (size_t)b * 65536 + hw;
    float*        oq  = out + O_ZQ + (size_t)b * 65536 + hw;
    const float4* ek4 = (const float4*)emb + (size_t)k * 16;
    float* dst = zf + (size_t)pos * 64;

    float lacc = 0.f;
#pragma unroll
    for (int i = 0; i < 16; ++i) {
        float4 e = ek4[i];
        float z0 = zb[(i * 4 + 0) * 1024];
        float z1 = zb[(i * 4 + 1) * 1024];
        float z2 = zb[(i * 4 + 2) * 1024];
        float z3 = zb[(i * 4 + 3) * 1024];
        *(float4*)&dst[i * 4] = make_float4(z0, z1, z2, z3);
        oq[(i * 4 + 0) * 1024] = z0 + (e.x - z0);
        oq[(i * 4 + 1) * 1024] = z1 + (e.y - z1);
        oq[(i * 4 + 2) * 1024] = z2 + (e.z - z2);
        oq[(i * 4 + 3) * 1024] = z3 + (e.w - z3);
        float d0 = z0 - e.x, d1 = z1 - e.y, d2 = z2 - e.z, d3 = z3 - e.w;
        lacc = fmaf(d0, d0, lacc);
        lacc = fmaf(d1, d1, lacc);
        lacc = fmaf(d2, d2, lacc);
        lacc = fmaf(d3, d3, lacc);
    }

    for (int off = 32; off; off >>= 1) lacc += __shfl_down(lacc, off);
    if ((tid & 63) == 0) atomicAdd(loss_acc, lacc);
}

// ---------------------------------------------------------------------------
// Kernel 4b (sep path): counting-sort z rows into O_ZQ scratch + loss.
// ---------------------------------------------------------------------------
__global__ __launch_bounds__(256) void vq_scatter_sep(
    const float* __restrict__ z, const float* __restrict__ emb,
    float* __restrict__ out, unsigned* __restrict__ cursor,
    float* __restrict__ loss_acc)
{
    const int tid = threadIdx.x;
    const int n   = blockIdx.x * 256 + tid;
    const int b   = n >> 10;
    const int hw  = n & 1023;
    const int k   = (int)out[O_IDX + n];

    const unsigned pos = atomicAdd(&cursor[k], 1u);
    const float*  zb  = z + (size_t)b * 65536 + hw;
    const float4* ek4 = (const float4*)emb + (size_t)k * 16;
    float* dst = out + O_ZQ + (size_t)pos * 64;

    float lacc = 0.f;
#pragma unroll
    for (int i = 0; i < 16; ++i) {
        float4 e = ek4[i];
        float z0 = zb[(i * 4 + 0) * 1024];
        float z1 = zb[(i * 4 + 1) * 1024];
        float z2 = zb[(i * 4 + 2) * 1024];
        float z3 = zb[(i * 4 + 3) * 1024];
        *(float4*)&dst[i * 4] = make_float4(z0, z1, z2, z3);
        float d0 = z0 - e.x, d1 = z1 - e.y, d2 = z2 - e.z, d3 = z3 - e.w;
        lacc = fmaf(d0, d0, lacc);
        lacc = fmaf(d1, d1, lacc);
        lacc = fmaf(d2, d2, lacc);
        lacc = fmaf(d3, d3, lacc);
    }

    for (int off = 32; off; off >>= 1) lacc += __shfl_down(lacc, off);
    if ((tid & 63) == 0) atomicAdd(loss_acc, lacc);
}

// ---------------------------------------------------------------------------
// Kernel 5: dw + EMA update from sorted zf (coalesced). grid 1024 x 256.
// ---------------------------------------------------------------------------
__global__ __launch_bounds__(256) void vq_upd_kernel(
    const float* __restrict__ zf, const unsigned* __restrict__ offs,
    const unsigned* __restrict__ counts, const float* __restrict__ ema_w,
    const float* __restrict__ n_val, const float* __restrict__ loss_acc,
    float* __restrict__ out)
{
    __shared__ float red[4][64];
    const int k   = blockIdx.x;
    const int tid = threadIdx.x;
    const int d   = tid & 63;
    const int q   = tid >> 6;
    const unsigned off = offs[k];
    const unsigned cnt = counts[k];

    float acc = 0.f;
    unsigned j = q;
    for (; j + 12 < cnt; j += 16) {
        float v0 = zf[(size_t)(off + j)      * 64 + d];
        float v1 = zf[(size_t)(off + j + 4)  * 64 + d];
        float v2 = zf[(size_t)(off + j + 8)  * 64 + d];
        float v3 = zf[(size_t)(off + j + 12) * 64 + d];
        acc += v0; acc += v1; acc += v2; acc += v3;
    }
    for (; j < cnt; j += 4) acc += zf[(size_t)(off + j) * 64 + d];

    red[q][d] = acc;
    __syncthreads();
    if (q == 0) {
        float dw = red[0][d] + red[1][d] + red[2][d] + red[3][d];
        float nw = 0.99f * ema_w[k * 64 + d] + 0.01f * dw;
        out[O_EMAW + k * 64 + d] = nw;
        float n   = n_val[0];
        float ncs = out[O_NCS + k];
        float csv = (ncs + 1e-5f) / (n + 1024e-5f) * n;
        out[O_EMB + k * 64 + d] = nw / csv;
    }
    if (k == 0 && tid == 0)
        out[O_LOSS] = 0.25f * loss_acc[0] / (float)NELEM;
}

// ---------------------------------------------------------------------------
// Kernel 6 (sep path only): final z_q_st writer. grid 512 x 256.
// ---------------------------------------------------------------------------
__global__ __launch_bounds__(256) void vq_zqwrite_kernel(
    const float* __restrict__ z, const float* __restrict__ emb,
    float* __restrict__ out)
{
    const int tid = threadIdx.x;
    const int n   = blockIdx.x * 128 + (tid & 127);
    const int h   = tid >> 7;
    const int b   = n >> 10;
    const int hw  = n & 1023;
    const int k   = (int)out[O_IDX + n];

    const float*  zb  = z   + ((size_t)(b * D + h * 32)) * HW + hw;
    float*        oq  = out + O_ZQ + ((size_t)(b * D + h * 32)) * HW + hw;
    const float4* ek4 = (const float4*)emb + (size_t)k * 16 + h * 8;

#pragma unroll
    for (int i = 0; i < 8; ++i) {
        float4 e = ek4[i];
        float z0 = zb[(i * 4 + 0) * HW];
        float z1 = zb[(i * 4 + 1) * HW];
        float z2 = zb[(i * 4 + 2) * HW];
        float z3 = zb[(i * 4 + 3) * HW];
        oq[(i * 4 + 0) * HW] = z0 + (e.x - z0);
        oq[(i * 4 + 1) * HW] = z1 + (e.y - z1);
        oq[(i * 4 + 2) * HW] = z2 + (e.z - z2);
        oq[(i * 4 + 3) * HW] = z3 + (e.w - z3);
    }
}

// ---------------------------------------------------------------------------
extern "C" void kernel_launch(void* const* d_in, const int* in_sizes, int n_in,
                              void* d_out, int out_size, void* d_ws, size_t ws_size,
                              hipStream_t stream) {
    const float* z     = (const float*)d_in[0];
    const float* emb   = (const float*)d_in[1];
    const float* cs    = (const float*)d_in[2];
    const float* ema_w = (const float*)d_in[3];
    float* out = (float*)d_out;

    char* W = (char*)d_ws;
    short*    eh_g   = (short*)(W + WB_EH);
    short*    el_g   = (short*)(W + WB_EL);
    float*    esq    = (float*)(W + WB_ESQ);
    unsigned* offs   = (unsigned*)(W + WB_OFFS);
    unsigned* cursor = (unsigned*)(W + WB_CURSOR);
    unsigned* counts = (unsigned*)(W + WB_COUNTS);
    float*    lossa  = (float*)(W + WB_LOSSN);
    float*    n_val  = lossa + 1;
    unsigned* rcnt   = (unsigned*)(W + WB_LOSSN + 8);
    int*      rlist  = (int*)(W + WB_RLIST);
    float*    zf     = (float*)(W + WB_ZF);

    const bool fused = ws_size >= (size_t)WS_NEED_FUSED;

    vq_prep_e<<<256, 256, 0, stream>>>(emb, (ushort*)eh_g, (ushort*)el_g, esq,
                                       counts);
    vq_dist_kernel<<<512, 256, 0, stream>>>(z, eh_g, el_g, esq, out, counts,
                                            rcnt, rlist);
    vq_rescore<<<128, 256, 0, stream>>>(z, emb, esq, rcnt, rlist, out, counts);
    vq_scan_kernel<<<1, 1024, 0, stream>>>(counts, cs, offs, cursor, out, n_val);
    if (fused) {
        vq_scatter_fused<<<256, 256, 0, stream>>>(z, emb, out, zf, cursor, lossa);
        vq_upd_kernel<<<1024, 256, 0, stream>>>(zf, offs, counts, ema_w,
                                                n_val, lossa, out);
    } else {
        vq_scatter_sep<<<256, 256, 0, stream>>>(z, emb, out, cursor, lossa);
        vq_upd_kernel<<<1024, 256, 0, stream>>>(out + O_ZQ, offs, counts, ema_w,
                                                n_val, lossa, out);
        vq_zqwrite_kernel<<<512, 256, 0, stream>>>(z, emb, out);
    }
}

// Round 10
// 215.085 us; speedup vs baseline: 5.1777x; 1.0157x over previous
//
#include <hip/hip_runtime.h>
#include <stdint.h>

typedef unsigned short ushort;
typedef __attribute__((ext_vector_type(8)))  short bfrag;   // 8 bf16 = 4 VGPR
typedef __attribute__((ext_vector_type(16))) float f32x16;  // MFMA 32x32 acc

#define D      64
#define K      1024
#define HW     1024
#define NROWS  65536
#define NELEM  (NROWS * 64)
#define BAND   0.01f

// Output layout (floats, reference return order)
#define O_ZQ   0
#define O_LOSS 4194304
#define O_IDX  4194305
#define O_NCS  4259841
#define O_EMAW 4260865
#define O_EMB  4326401

// Workspace layout (bytes)
#define WB_EH     0x00000   // 1024x64 u16 = 128K
#define WB_EL     0x20000   // 128K
#define WB_ESQ    0x40000   // 1024 f32
#define WB_OFFS   0x41000
#define WB_CURSOR 0x42000
#define WB_COUNTS 0x43000   // zeroed by prep_e
#define WB_LOSSN  0x44000   // loss f32, n f32, rcnt u32 (zeroed by prep_e)
#define WB_RLIST  0x45000   // 65536 i32 = 256K -> ends 0x85000
#define WB_ZF     0x100000  // 16 MB sorted rows (fused path only)
#define WS_NEED_FUSED (0x100000 + 0x1000000)

__device__ __forceinline__ unsigned bf16r(float x) {   // RNE f32->bf16 bits
    unsigned u = __float_as_uint(x);
    return (u + 0x7FFFu + ((u >> 16) & 1u)) >> 16;
}
__device__ __forceinline__ float bf16f(unsigned h) {
    return __uint_as_float(h << 16);
}

// ---------------------------------------------------------------------------
// Kernel 0: wave-per-code esq + bf16 hi/lo split; block 0 zeroes control blk.
// grid 256 x 256 (4 waves/block).
// ---------------------------------------------------------------------------
__global__ __launch_bounds__(256) void vq_prep_e(
    const float* __restrict__ emb, ushort* __restrict__ eh,
    ushort* __restrict__ el, float* __restrict__ esq,
    unsigned* __restrict__ zero_region)
{
    const int tid = threadIdx.x;
    if (blockIdx.x == 0) {
#pragma unroll
        for (int i = 0; i < 8; ++i) zero_region[i * 256 + tid] = 0u;  // 8 KB
    }
    const int k = blockIdx.x * 4 + (tid >> 6);
    const int d = tid & 63;
    float v = emb[k * 64 + d];
    unsigned hh = bf16r(v);
    float rem = v - bf16f(hh);
    eh[k * 64 + d] = (ushort)hh;
    el[k * 64 + d] = (ushort)bf16r(rem);
    float a = v * v;
#pragma unroll
    for (int off = 32; off; off >>= 1) a += __shfl_xor(a, off);
    if (d == 0) esq[k] = a;
}

// ---------------------------------------------------------------------------
// Kernel 1: MFMA distance argmin. 256 thr (4 waves x 32 rows), grid 512.
// Two independent MFMA chains (code-groups t0/t1) per chunk; setprio around
// the MFMA cluster; e-chunk LDS double-buffered (1 barrier/chunk).
// ---------------------------------------------------------------------------
__global__ __launch_bounds__(256, 2) void vq_dist_kernel(
    const float* __restrict__ z, const short* __restrict__ eh_g,
    const short* __restrict__ el_g, const float* __restrict__ esq_g,
    float* __restrict__ out, unsigned* __restrict__ counts,
    unsigned* __restrict__ rcnt, int* __restrict__ rlist)
{
    __shared__ __align__(16) short zh_lds[128 * 64];      // 16 KB
    __shared__ __align__(16) short zl_lds[128 * 64];      // 16 KB
    __shared__ __align__(16) short eh_lds[2][64 * 64];    // 16 KB
    __shared__ __align__(16) short el_lds[2][64 * 64];    // 16 KB
    __shared__ float esq_lds[1024];                       // 4 KB

    const int tid  = threadIdx.x;
    const int lane = tid & 63;
    const int wave = tid >> 6;
    const int col  = lane & 31;
    const int h    = lane >> 5;
    const int n0   = blockIdx.x * 128;
    const int b    = n0 >> 10;
    const int hw0  = n0 & 1023;

    // ---- stage z -> LDS as bf16 hi/lo of (-2*z), XOR-swizzled 16B units
    for (int it = 0; it < 4; ++it) {
        int task = it * 256 + tid;
        int row  = task & 127;
        int kq   = task >> 7;
        const float* zp = z + (size_t)b * 65536 + (size_t)(kq * 8) * 1024 + hw0 + row;
        bfrag vh, vl;
#pragma unroll
        for (int m = 0; m < 8; ++m) {
            float t = -2.0f * zp[m * 1024];
            unsigned hh = bf16r(t);
            float rem = t - bf16f(hh);
            vh[m] = (short)hh;
            vl[m] = (short)bf16r(rem);
        }
        int unit = kq ^ (row & 7);
        *(bfrag*)&zh_lds[row * 64 + unit * 8] = vh;
        *(bfrag*)&zl_lds[row * 64 + unit * 8] = vl;
    }
    for (int it = 0; it < 4; ++it) {
        int t = it * 256 + tid;
        esq_lds[t] = esq_g[t];
    }

    // ---- e-chunk staging helpers (64 codes/chunk)
    bfrag pfh[2], pfl[2];
    auto loadE = [&](int cb) {
#pragma unroll
        for (int q = 0; q < 2; ++q) {
            int u = q * 256 + tid;
            int code = u >> 3, m = u & 7;
            pfh[q] = *(const bfrag*)&eh_g[(size_t)(cb + code) * 64 + m * 8];
            pfl[q] = *(const bfrag*)&el_g[(size_t)(cb + code) * 64 + m * 8];
        }
    };
    auto writeE = [&](int buf) {
#pragma unroll
        for (int q = 0; q < 2; ++q) {
            int u = q * 256 + tid;
            int code = u >> 3, m = u & 7;
            int unit = ((code >> 5) * 4 + (m >> 1)) * 64 +
                       ((((m & 1) << 5) | (code & 31)) ^ (m & 7));
            *(bfrag*)&eh_lds[buf][unit * 8] = pfh[q];
            *(bfrag*)&el_lds[buf][unit * 8] = pfl[q];
        }
    };

    loadE(0);
    writeE(0);
    loadE(64);
    __syncthreads();    // z staging + esq + e-buf0 visible

    // ---- A-frags (scaled -2z), reused over all 1024 codes
    const int wrow = wave * 32 + col;
    bfrag zhA[4], zlA[4];
#pragma unroll
    for (int j = 0; j < 4; ++j) {
        int kq = j * 2 + h;
        int unit = kq ^ (wrow & 7);
        zhA[j] = *(const bfrag*)&zh_lds[wrow * 64 + unit * 8];
        zlA[j] = *(const bfrag*)&zl_lds[wrow * 64 + unit * 8];
    }

    float t1s[16], t2s[16];
    unsigned t1c[16];
#pragma unroll
    for (int i = 0; i < 16; ++i) { t1s[i] = INFINITY; t2s[i] = INFINITY; t1c[i] = 0; }

    for (int ch = 0; ch < 16; ++ch) {
        const int cb  = ch * 64;
        const int buf = ch & 1;

        // load BOTH code-groups' B-frags up front (16 ds_read_b128)
        bfrag ehB0[4], elB0[4], ehB1[4], elB1[4];
#pragma unroll
        for (int j = 0; j < 4; ++j) {
            int m = j * 2 + h;
            int sw = (((h << 5) | col) ^ (m & 7));
            ehB0[j] = *(const bfrag*)&eh_lds[buf][(j * 64 + sw) * 8];
            elB0[j] = *(const bfrag*)&el_lds[buf][(j * 64 + sw) * 8];
            ehB1[j] = *(const bfrag*)&eh_lds[buf][((4 + j) * 64 + sw) * 8];
            elB1[j] = *(const bfrag*)&el_lds[buf][((4 + j) * 64 + sw) * 8];
        }
        const float esq0 = esq_lds[cb + col];
        const float esq1 = esq_lds[cb + 32 + col];
        const unsigned c0 = cb + col;
        const unsigned c1 = cb + 32 + col;

        f32x16 acc0, acc1;
#pragma unroll
        for (int i = 0; i < 16; ++i) { acc0[i] = esq0; acc1[i] = esq1; }

        __builtin_amdgcn_s_setprio(1);
#pragma unroll
        for (int j = 0; j < 4; ++j) {
            acc0 = __builtin_amdgcn_mfma_f32_32x32x16_bf16(zhA[j], ehB0[j], acc0, 0, 0, 0);
            acc1 = __builtin_amdgcn_mfma_f32_32x32x16_bf16(zhA[j], ehB1[j], acc1, 0, 0, 0);
        }
#pragma unroll
        for (int j = 0; j < 4; ++j) {
            acc0 = __builtin_amdgcn_mfma_f32_32x32x16_bf16(zhA[j], elB0[j], acc0, 0, 0, 0);
            acc1 = __builtin_amdgcn_mfma_f32_32x32x16_bf16(zhA[j], elB1[j], acc1, 0, 0, 0);
        }
#pragma unroll
        for (int j = 0; j < 4; ++j) {
            acc0 = __builtin_amdgcn_mfma_f32_32x32x16_bf16(zlA[j], ehB0[j], acc0, 0, 0, 0);
            acc1 = __builtin_amdgcn_mfma_f32_32x32x16_bf16(zlA[j], ehB1[j], acc1, 0, 0, 0);
        }
        __builtin_amdgcn_s_setprio(0);

        // refill the other buffer while scores update
        if (ch < 15) {
            writeE(buf ^ 1);
            if (ch < 14) loadE(cb + 128);
        }

#pragma unroll
        for (int i = 0; i < 16; ++i) {
            float s0 = acc0[i];
            t2s[i] = __builtin_amdgcn_fmed3f(t1s[i], t2s[i], s0);
            bool lt0 = s0 < t1s[i];
            t1s[i] = fminf(t1s[i], s0);
            t1c[i] = lt0 ? c0 : t1c[i];
            float s1 = acc1[i];
            t2s[i] = __builtin_amdgcn_fmed3f(t1s[i], t2s[i], s1);
            bool lt1 = s1 < t1s[i];
            t1s[i] = fminf(t1s[i], s1);
            t1c[i] = lt1 ? c1 : t1c[i];
        }
        __syncthreads();
    }

    // ---- per-row cross-lane argmin + top-2 gap, C/D row = (i&3)+8*(i>>2)+4h
#pragma unroll
    for (int i = 0; i < 16; ++i) {
        float v = t1s[i], w = t2s[i];
        int   c = (int)t1c[i];
#pragma unroll
        for (int m = 1; m < 32; m <<= 1) {
            float ov = __shfl_xor(v, m);
            int   oc = __shfl_xor(c, m);
            float ow = __shfl_xor(w, m);
            float mx = fmaxf(v, ov);
            w = fminf(fminf(w, ow), mx);
            bool take = (ov < v) || (ov == v && oc < c);
            v = take ? ov : v;
            c = take ? oc : c;
        }
        if ((lane & 31) == 0) {
            int row = (i & 3) + ((i >> 2) << 3) + (h << 2);
            int n = n0 + wave * 32 + row;
            out[O_IDX + n] = (float)c;
            atomicAdd(&counts[c], 1u);
            if (w - v < BAND) {
                unsigned p = atomicAdd(rcnt, 1u);
                rlist[p] = n;
            }
        }
    }
}

// ---------------------------------------------------------------------------
// Kernel 2: exact fp32 rescore of uncertified rows. grid 128 x 256.
// ---------------------------------------------------------------------------
__global__ __launch_bounds__(256) void vq_rescore(
    const float* __restrict__ z, const float* __restrict__ emb,
    const float* __restrict__ esq, const unsigned* __restrict__ rcnt,
    const int* __restrict__ rlist, float* __restrict__ out,
    unsigned* __restrict__ counts)
{
    __shared__ float zrow[64];
    __shared__ float rs[4];
    __shared__ int   rc[4];
    const int tid = threadIdx.x;
    const unsigned cnt = rcnt[0];

    for (unsigned i = blockIdx.x; i < cnt; i += gridDim.x) {
        const int n = rlist[i];
        const int b = n >> 10, hw = n & 1023;
        __syncthreads();
        if (tid < 64) zrow[tid] = z[(size_t)b * 65536 + (size_t)tid * 1024 + hw];
        __syncthreads();

        float best = INFINITY; int bc = 0;
        for (int rep = 0; rep < 4; ++rep) {
            int code = rep * 256 + tid;
            const float4* er = (const float4*)(emb + (size_t)code * 64);
            float a0 = 0.f, a1 = 0.f, a2 = 0.f, a3 = 0.f;
#pragma unroll
            for (int q = 0; q < 16; ++q) {
                float4 e = er[q];
                a0 = fmaf(zrow[q * 4 + 0], e.x, a0);
                a1 = fmaf(zrow[q * 4 + 1], e.y, a1);
                a2 = fmaf(zrow[q * 4 + 2], e.z, a2);
                a3 = fmaf(zrow[q * 4 + 3], e.w, a3);
            }
            float s = fmaf(-2.f, (a0 + a1) + (a2 + a3), esq[code]);
            if (s < best || (s == best && code < bc)) { best = s; bc = code; }
        }
        for (int m = 1; m < 64; m <<= 1) {
            float ov = __shfl_xor(best, m);
            int   oc = __shfl_xor(bc, m);
            bool take = (ov < best) || (ov == best && oc < bc);
            best = take ? ov : best;
            bc   = take ? oc : bc;
        }
        if ((tid & 63) == 0) { rs[tid >> 6] = best; rc[tid >> 6] = bc; }
        __syncthreads();
        if (tid == 0) {
            float fb = rs[0]; int fc = rc[0];
#pragma unroll
            for (int q = 1; q < 4; ++q) {
                bool take = (rs[q] < fb) || (rs[q] == fb && rc[q] < fc);
                fb = take ? rs[q] : fb;
                fc = take ? rc[q] : fc;
            }
            int old = (int)out[O_IDX + n];
            if (fc != old) {
                atomicAdd(&counts[old], (unsigned)-1);
                atomicAdd(&counts[fc], 1u);
                out[O_IDX + n] = (float)fc;
            }
        }
    }
}

// ---------------------------------------------------------------------------
// Kernel 3: scan. 1 block x 1024.
// ---------------------------------------------------------------------------
__global__ __launch_bounds__(1024) void vq_scan_kernel(
    const unsigned* __restrict__ counts, const float* __restrict__ cs,
    unsigned* __restrict__ offs, unsigned* __restrict__ cursor,
    float* __restrict__ out, float* __restrict__ n_val)
{
    __shared__ unsigned wtot[16], wbase[16];
    __shared__ float    fred[16];
    const int k    = threadIdx.x;
    const int lane = k & 63;
    const int w    = k >> 6;

    unsigned c = counts[k];
    unsigned v = c;
#pragma unroll
    for (int off = 1; off < 64; off <<= 1) {
        unsigned t = __shfl_up(v, off);
        if (lane >= off) v += t;
    }
    if (lane == 63) wtot[w] = v;

    float ncs = 0.99f * cs[k] + 0.01f * (float)c;
    out[O_NCS + k] = ncs;
    float s = ncs;
#pragma unroll
    for (int off = 32; off; off >>= 1) s += __shfl_down(s, off);
    if (lane == 0) fred[w] = s;

    __syncthreads();
    if (k == 0) {
        unsigned base = 0; float nt = 0.f;
#pragma unroll
        for (int i = 0; i < 16; ++i) {
            wbase[i] = base;
            base += wtot[i];
            nt += fred[i];
        }
        n_val[0] = nt;
    }
    __syncthreads();
    unsigned o = wbase[w] + (v - c);
    offs[k]   = o;
    cursor[k] = o;
}

// ---------------------------------------------------------------------------
// Kernel 4a (fused, ws >= 17.1MB): one z pass -> z_q_st + sorted zf(ws) +
// loss. grid 256 x 256.
// ---------------------------------------------------------------------------
__global__ __launch_bounds__(256) void vq_scatter_fused(
    const float* __restrict__ z, const float* __restrict__ emb,
    float* __restrict__ out, float* __restrict__ zf,
    unsigned* __restrict__ cursor, float* __restrict__ loss_acc)
{
    const int tid = threadIdx.x;
    const int n   = blockIdx.x * 256 + tid;
    const int b   = n >> 10;
    const int hw  = n & 1023;
    const int k   = (int)out[O_IDX + n];

    const unsigned pos = atomicAdd(&cursor[k], 1u);
    const float*  zb  = z   + (size_t)b * 65536 + hw;
    float*        oq  = out + O_ZQ + (size_t)b * 65536 + hw;
    const float4* ek4 = (const float4*)emb + (size_t)k * 16;
    float* dst = zf + (size_t)pos * 64;

    float lacc = 0.f;
#pragma unroll
    for (int i = 0; i < 16; ++i) {
        float4 e = ek4[i];
        float z0 = zb[(i * 4 + 0) * 1024];
        float z1 = zb[(i * 4 + 1) * 1024];
        float z2 = zb[(i * 4 + 2) * 1024];
        float z3 = zb[(i * 4 + 3) * 1024];
        *(float4*)&dst[i * 4] = make_float4(z0, z1, z2, z3);
        oq[(i * 4 + 0) * 1024] = z0 + (e.x - z0);
        oq[(i * 4 + 1) * 1024] = z1 + (e.y - z1);
        oq[(i * 4 + 2) * 1024] = z2 + (e.z - z2);
        oq[(i * 4 + 3) * 1024] = z3 + (e.w - z3);
        float d0 = z0 - e.x, d1 = z1 - e.y, d2 = z2 - e.z, d3 = z3 - e.w;
        lacc = fmaf(d0, d0, lacc);
        lacc = fmaf(d1, d1, lacc);
        lacc = fmaf(d2, d2, lacc);
        lacc = fmaf(d3, d3, lacc);
    }

    for (int off = 32; off; off >>= 1) lacc += __shfl_down(lacc, off);
    if ((tid & 63) == 0) atomicAdd(loss_acc, lacc);
}

// ---------------------------------------------------------------------------
// Kernel 4b (sep path): counting-sort z rows into O_ZQ scratch + loss.
// ---------------------------------------------------------------------------
__global__ __launch_bounds__(256) void vq_scatter_sep(
    const float* __restrict__ z, const float* __restrict__ emb,
    float* __restrict__ out, unsigned* __restrict__ cursor,
    float* __restrict__ loss_acc)
{
    const int tid = threadIdx.x;
    const int n   = blockIdx.x * 256 + tid;
    const int b   = n >> 10;
    const int hw  = n & 1023;
    const int k   = (int)out[O_IDX + n];

    const unsigned pos = atomicAdd(&cursor[k], 1u);
    const float*  zb  = z + (size_t)b * 65536 + hw;
    const float4* ek4 = (const float4*)emb + (size_t)k * 16;
    float* dst = out + O_ZQ + (size_t)pos * 64;

    float lacc = 0.f;
#pragma unroll
    for (int i = 0; i < 16; ++i) {
        float4 e = ek4[i];
        float z0 = zb[(i * 4 + 0) * 1024];
        float z1 = zb[(i * 4 + 1) * 1024];
        float z2 = zb[(i * 4 + 2) * 1024];
        float z3 = zb[(i * 4 + 3) * 1024];
        *(float4*)&dst[i * 4] = make_float4(z0, z1, z2, z3);
        float d0 = z0 - e.x, d1 = z1 - e.y, d2 = z2 - e.z, d3 = z3 - e.w;
        lacc = fmaf(d0, d0, lacc);
        lacc = fmaf(d1, d1, lacc);
        lacc = fmaf(d2, d2, lacc);
        lacc = fmaf(d3, d3, lacc);
    }

    for (int off = 32; off; off >>= 1) lacc += __shfl_down(lacc, off);
    if ((tid & 63) == 0) atomicAdd(loss_acc, lacc);
}

// ---------------------------------------------------------------------------
// Kernel 5: dw + EMA update from sorted zf (coalesced). grid 1024 x 256.
// ---------------------------------------------------------------------------
__global__ __launch_bounds__(256) void vq_upd_kernel(
    const float* __restrict__ zf, const unsigned* __restrict__ offs,
    const unsigned* __restrict__ counts, const float* __restrict__ ema_w,
    const float* __restrict__ n_val, const float* __restrict__ loss_acc,
    float* __restrict__ out)
{
    __shared__ float red[4][64];
    const int k   = blockIdx.x;
    const int tid = threadIdx.x;
    const int d   = tid & 63;
    const int q   = tid >> 6;
    const unsigned off = offs[k];
    const unsigned cnt = counts[k];

    float acc = 0.f;
    unsigned j = q;
    for (; j + 12 < cnt; j += 16) {
        float v0 = zf[(size_t)(off + j)      * 64 + d];
        float v1 = zf[(size_t)(off + j + 4)  * 64 + d];
        float v2 = zf[(size_t)(off + j + 8)  * 64 + d];
        float v3 = zf[(size_t)(off + j + 12) * 64 + d];
        acc += v0; acc += v1; acc += v2; acc += v3;
    }
    for (; j < cnt; j += 4) acc += zf[(size_t)(off + j) * 64 + d];

    red[q][d] = acc;
    __syncthreads();
    if (q == 0) {
        float dw = red[0][d] + red[1][d] + red[2][d] + red[3][d];
        float nw = 0.99f * ema_w[k * 64 + d] + 0.01f * dw;
        out[O_EMAW + k * 64 + d] = nw;
        float n   = n_val[0];
        float ncs = out[O_NCS + k];
        float csv = (ncs + 1e-5f) / (n + 1024e-5f) * n;
        out[O_EMB + k * 64 + d] = nw / csv;
    }
    if (k == 0 && tid == 0)
        out[O_LOSS] = 0.25f * loss_acc[0] / (float)NELEM;
}

// ---------------------------------------------------------------------------
// Kernel 6 (sep path only): final z_q_st writer. grid 512 x 256.
// ---------------------------------------------------------------------------
__global__ __launch_bounds__(256) void vq_zqwrite_kernel(
    const float* __restrict__ z, const float* __restrict__ emb,
    float* __restrict__ out)
{
    const int tid = threadIdx.x;
    const int n   = blockIdx.x * 128 + (tid & 127);
    const int h   = tid >> 7;
    const int b   = n >> 10;
    const int hw  = n & 1023;
    const int k   = (int)out[O_IDX + n];

    const float*  zb  = z   + ((size_t)(b * D + h * 32)) * HW + hw;
    float*        oq  = out + O_ZQ + ((size_t)(b * D + h * 32)) * HW + hw;
    const float4* ek4 = (const float4*)emb + (size_t)k * 16 + h * 8;

#pragma unroll
    for (int i = 0; i < 8; ++i) {
        float4 e = ek4[i];
        float z0 = zb[(i * 4 + 0) * HW];
        float z1 = zb[(i * 4 + 1) * HW];
        float z2 = zb[(i * 4 + 2) * HW];
        float z3 = zb[(i * 4 + 3) * HW];
        oq[(i * 4 + 0) * HW] = z0 + (e.x - z0);
        oq[(i * 4 + 1) * HW] = z1 + (e.y - z1);
        oq[(i * 4 + 2) * HW] = z2 + (e.z - z2);
        oq[(i * 4 + 3) * HW] = z3 + (e.w - z3);
    }
}

// ---------------------------------------------------------------------------
extern "C" void kernel_launch(void* const* d_in, const int* in_sizes, int n_in,
                              void* d_out, int out_size, void* d_ws, size_t ws_size,
                              hipStream_t stream) {
    const float* z     = (const float*)d_in[0];
    const float* emb   = (const float*)d_in[1];
    const float* cs    = (const float*)d_in[2];
    const float* ema_w = (const float*)d_in[3];
    float* out = (float*)d_out;

    char* W = (char*)d_ws;
    short*    eh_g   = (short*)(W + WB_EH);
    short*    el_g   = (short*)(W + WB_EL);
    float*    esq    = (float*)(W + WB_ESQ);
    unsigned* offs   = (unsigned*)(W + WB_OFFS);
    unsigned* cursor = (unsigned*)(W + WB_CURSOR);
    unsigned* counts = (unsigned*)(W + WB_COUNTS);
    float*    lossa  = (float*)(W + WB_LOSSN);
    float*    n_val  = lossa + 1;
    unsigned* rcnt   = (unsigned*)(W + WB_LOSSN + 8);
    int*      rlist  = (int*)(W + WB_RLIST);
    float*    zf     = (float*)(W + WB_ZF);

    const bool fused = ws_size >= (size_t)WS_NEED_FUSED;

    vq_prep_e<<<256, 256, 0, stream>>>(emb, (ushort*)eh_g, (ushort*)el_g, esq,
                                       counts);
    vq_dist_kernel<<<512, 256, 0, stream>>>(z, eh_g, el_g, esq, out, counts,
                                            rcnt, rlist);
    vq_rescore<<<128, 256, 0, stream>>>(z, emb, esq, rcnt, rlist, out, counts);
    vq_scan_kernel<<<1, 1024, 0, stream>>>(counts, cs, offs, cursor, out, n_val);
    if (fused) {
        vq_scatter_fused<<<256, 256, 0, stream>>>(z, emb, out, zf, cursor, lossa);
        vq_upd_kernel<<<1024, 256, 0, stream>>>(zf, offs, counts, ema_w,
                                                n_val, lossa, out);
    } else {
        vq_scatter_sep<<<256, 256, 0, stream>>>(z, emb, out, cursor, lossa);
        vq_upd_kernel<<<1024, 256, 0, stream>>>(out + O_ZQ, offs, counts, ema_w,
                                                n_val, lossa, out);
        vq_zqwrite_kernel<<<512, 256, 0, stream>>>(z, emb, out);
    }
}